// Round 7
// baseline (231.120 us; speedup 1.0000x reference)
//
#include <hip/hip_runtime.h>
#include <math.h>

#define NSEQ 1536
#define HD3  1536      // fused qkv row stride
#define RKLD 512       // rel_k row stride
#define RLEN 3071
#define NB   12

typedef __attribute__((ext_vector_type(8))) short bf16x8;
typedef __attribute__((ext_vector_type(4))) float f32x4;
typedef _Float16 f16x8 __attribute__((ext_vector_type(8)));
typedef _Float16 f16x4 __attribute__((ext_vector_type(4)));

__device__ __forceinline__ unsigned short f2bf(float f) {
    union { float f; unsigned u; } v; v.f = f;
    unsigned r = v.u + 0x7fffu + ((v.u >> 16) & 1u);
    return (unsigned short)(r >> 16);
}
__device__ __forceinline__ float bf2f(unsigned short s) {
    union { unsigned u; float f; } v; v.u = ((unsigned)s) << 16;
    return v.f;
}
__device__ __forceinline__ unsigned short f2h(float f) {
    union { _Float16 h; unsigned short u; } c; c.h = (_Float16)f; return c.u;
}
__device__ __forceinline__ void cp16(const void* g, void* l) {
    __builtin_amdgcn_global_load_lds(
        (const __attribute__((address_space(1))) void*)g,
        (__attribute__((address_space(3))) void*)l, 16, 0, 0);
}

// LDS swizzles: keep 8-elem chunks contiguous; XOR chunk id with row bits to
// break power-of-2 stride bank conflicts.
#define KSWZ(row, d) ((row) * 64 + (((((d) >> 3) ^ ((row) & 7))) << 3) + ((d) & 7))
#define PSWZ(r, j)   ((r) * 128 + (((((j) >> 3) ^ ((r) & 15))) << 3) + ((j) & 7))
#define VSTR 136     // Vt row stride in elems (272B: 16B-aligned, non-pow2)

// ---------------------------------------------------------------------------
// fp32 -> f16: x (4608 blocks) and pos_embed (576 blocks) in one launch.
// ---------------------------------------------------------------------------
__global__ __launch_bounds__(256) void split2_f16(
    const float* __restrict__ X, _Float16* __restrict__ HX,
    const float* __restrict__ P, _Float16* __restrict__ HP)
{
    const int bid = blockIdx.x;
    const float* src; _Float16* dst; int i;
    if (bid < 4608) {                    // 4608*256 == 1179648 exactly
        i = bid * 256 + threadIdx.x;
        src = X; dst = HX;
    } else {
        i = (bid - 4608) * 256 + threadIdx.x;
        if (i >= 147408) return;         // 3071*192/4
        src = P; dst = HP;
    }
    float4 v = ((const float4*)src)[i];
    union { _Float16 h[4]; ushort4 u; } c;
    c.h[0] = (_Float16)v.x; c.h[1] = (_Float16)v.y;
    c.h[2] = (_Float16)v.z; c.h[3] = (_Float16)v.w;
    ((ushort4*)dst)[i] = c.u;
}

// ---------------------------------------------------------------------------
// Weight transpose (generic): W[K][N] f32 -> T[n_off+N][ldt] f16
// ---------------------------------------------------------------------------
__device__ __forceinline__ void wsplit_body16(
    const float* __restrict__ W, _Float16* __restrict__ T,
    int K, int N, int n_off, int ldt, float scale, int bx, int by)
{
    __shared__ float tile[64][65];
    const int k0 = by * 64, n0 = bx * 64;
    const int t = threadIdx.x;
    const int rr = t >> 4, c4 = (t & 15) * 4;
#pragma unroll
    for (int p = 0; p < 4; ++p) {
        int r = p * 16 + rr;
        float4 v = *(const float4*)(W + (size_t)(k0 + r) * N + n0 + c4);
        tile[r][c4 + 0] = v.x; tile[r][c4 + 1] = v.y;
        tile[r][c4 + 2] = v.z; tile[r][c4 + 3] = v.w;
    }
    __syncthreads();
#pragma unroll
    for (int p = 0; p < 4; ++p) {
        int n = p * 16 + rr;
        union { _Float16 h[4]; ushort4 u; } cc;
        cc.h[0] = (_Float16)(tile[c4 + 0][n] * scale);
        cc.h[1] = (_Float16)(tile[c4 + 1][n] * scale);
        cc.h[2] = (_Float16)(tile[c4 + 2][n] * scale);
        cc.h[3] = (_Float16)(tile[c4 + 3][n] * scale);
        size_t o = (size_t)(n_off + n0 + n) * ldt + k0 + c4;
        *(ushort4*)(T + o) = cc.u;
    }
}

// One launch transposes all five weights: z=0..2 Wq/Wk/Wv, z=3 Wo, z=4 Wrel.
__global__ __launch_bounds__(256) void wsplit_all(
    const float* __restrict__ Wq, const float* __restrict__ Wk,
    const float* __restrict__ Wv, const float* __restrict__ Wo,
    const float* __restrict__ Wrel,
    _Float16* __restrict__ Tqkv, _Float16* __restrict__ To,
    _Float16* __restrict__ Trel)
{
    const int z = blockIdx.z;
    if (z < 3) {
        const float* W = (z == 0) ? Wq : (z == 1) ? Wk : Wv;
        wsplit_body16(W, Tqkv, 1536, 512, z * 512, 1536,
                      (z == 0) ? 0.125f : 1.f, blockIdx.x, blockIdx.y);
    } else if (z == 3) {
        wsplit_body16(Wo, To, 512, 1536, 0, 512, 1.f, blockIdx.y, blockIdx.x);
    } else {
        if (blockIdx.y >= 3) return;   // uniform per block, before any barrier
        wsplit_body16(Wrel, Trel, 192, 512, 0, 192, 1.f, blockIdx.x, blockIdx.y);
    }
}

// ---------------------------------------------------------------------------
// Single-term f16 MFMA GEMM, 64x64 tile, BK=64: C = A·B^T (+bias).
// 2-buffer single-barrier; 32KB LDS; KSWZ; XCD swizzle.
// omode 0: C f32 + bias. omode 1: QKV split store — cols<1024 f16 (Q,K),
// cols>=1024 bf16 (V: must pair with bf16 P in the PV MFMA). omode 2: f16.
// ---------------------------------------------------------------------------
__global__ __launch_bounds__(256) void gemm_f16k(
    const _Float16* __restrict__ A,   // [M][K] f16
    const _Float16* __restrict__ B,   // [N][K] f16 (pre-transposed weight)
    const float* __restrict__ bias, void* __restrict__ C,
    int M, int N, int K, int omode)
{
    __shared__ _Float16 sA[2][4096];    // [buf][64*64]
    __shared__ _Float16 sB[2][4096];
    const int t = threadIdx.x;
    const int wave = t >> 6, lane = t & 63;
    // XCD-aware bijective swizzle (nwg % 8 == 0 for all launches here)
    const int nwg = gridDim.x * gridDim.y;
    const int lin = blockIdx.y * gridDim.x + blockIdx.x;
    const int swz = (lin & 7) * (nwg >> 3) + (lin >> 3);
    const int bx = swz % gridDim.x, by = swz / gridDim.x;
    const int m0 = by * 64, n0 = bx * 64;
    const int wm = (wave >> 1) * 32, wn = (wave & 1) * 32;
    const int fr = lane & 15, quad = lane >> 4;

    f32x4 acc[2][2];
#pragma unroll
    for (int i = 0; i < 2; ++i)
#pragma unroll
        for (int j = 0; j < 2; ++j)
#pragma unroll
            for (int c = 0; c < 4; ++c) acc[i][j][c] = 0.f;

    const int nsteps = K >> 6;

#define STAGE(k0, buf)                                                        \
    {                                                                         \
        _Pragma("unroll")                                                     \
        for (int it = 0; it < 2; ++it) {                                      \
            int cidx = it * 256 + t;                                          \
            int row = cidx >> 3, slot = cidx & 7;                             \
            int gch = slot ^ (row & 7);                                       \
            size_t goA = (size_t)(m0 + row) * K + (k0) + gch * 8;             \
            size_t goB = (size_t)(n0 + row) * K + (k0) + gch * 8;             \
            cp16(A + goA, &sA[buf][it * 2048 + wave * 512]);                  \
            cp16(B + goB, &sB[buf][it * 2048 + wave * 512]);                  \
        }                                                                     \
    }

    STAGE(0, 0);
    for (int s = 0; s < nsteps; ++s) {
        const int buf = s & 1;
        __syncthreads();
        if (s + 1 < nsteps) STAGE((s + 1) * 64, buf ^ 1);

        f16x8 fa[2][2], fb[2][2];
#pragma unroll
        for (int ti = 0; ti < 2; ++ti)
#pragma unroll
            for (int kc = 0; kc < 2; ++kc) {
                fa[ti][kc] = *(const f16x8*)&sA[buf][KSWZ(wm + ti * 16 + fr,
                                                          kc * 32 + quad * 8)];
                fb[ti][kc] = *(const f16x8*)&sB[buf][KSWZ(wn + ti * 16 + fr,
                                                          kc * 32 + quad * 8)];
            }
#pragma unroll
        for (int ti = 0; ti < 2; ++ti)
#pragma unroll
            for (int tj = 0; tj < 2; ++tj)
#pragma unroll
                for (int kc = 0; kc < 2; ++kc)
                    acc[ti][tj] = __builtin_amdgcn_mfma_f32_16x16x32_f16(
                        fa[ti][kc], fb[tj][kc], acc[ti][tj], 0, 0, 0);
    }
#undef STAGE

    if (omode == 0) {
        float* Cf = (float*)C;
#pragma unroll
        for (int ti = 0; ti < 2; ++ti) {
            int rowb = m0 + wm + ti * 16 + quad * 4;
#pragma unroll
            for (int tj = 0; tj < 2; ++tj) {
                int col = n0 + wn + tj * 16 + fr;
                float bb = bias ? bias[col] : 0.f;
#pragma unroll
                for (int j2 = 0; j2 < 4; ++j2)
                    Cf[(size_t)(rowb + j2) * N + col] = acc[ti][tj][j2] + bb;
            }
        }
    } else {
        unsigned short* Cu = (unsigned short*)C;
        const bool vb = (omode == 1) && (n0 >= 1024);   // V region -> bf16
#pragma unroll
        for (int ti = 0; ti < 2; ++ti) {
            int rowb = m0 + wm + ti * 16 + quad * 4;
#pragma unroll
            for (int tj = 0; tj < 2; ++tj) {
                int col = n0 + wn + tj * 16 + fr;
#pragma unroll
                for (int j2 = 0; j2 < 4; ++j2) {
                    float v = acc[ti][tj][j2];
                    Cu[(size_t)(rowb + j2) * N + col] = vb ? f2bf(v) : f2h(v);
                }
            }
        }
    }
}

// ---------------------------------------------------------------------------
// drk[h][jj] = sum_d (rpb[h,d]-rcb[h,d]) * rk[jj, h*64+d]   (rk f16)
// ---------------------------------------------------------------------------
__global__ __launch_bounds__(256) void drk_kernel(
    const _Float16* __restrict__ rkh, const float* __restrict__ cb,
    const float* __restrict__ rb, float* __restrict__ drk)
{
    int idx = blockIdx.x * 256 + threadIdx.x;
    if (idx >= 8 * RLEN) return;
    int jj = idx >> 3, h = idx & 7;
    const _Float16* rrow = rkh + (size_t)jj * RKLD + h * 64;
    float s0 = 0, s1 = 0, s2 = 0, s3 = 0;
#pragma unroll
    for (int d4 = 0; d4 < 16; ++d4) {
        f16x4 rv = *(const f16x4*)(rrow + d4 * 4);
        float dx = rb[h * 64 + d4 * 4 + 0] - cb[h * 64 + d4 * 4 + 0];
        float dy = rb[h * 64 + d4 * 4 + 1] - cb[h * 64 + d4 * 4 + 1];
        float dz = rb[h * 64 + d4 * 4 + 2] - cb[h * 64 + d4 * 4 + 2];
        float dw = rb[h * 64 + d4 * 4 + 3] - cb[h * 64 + d4 * 4 + 3];
        s0 = fmaf(dx, (float)rv[0], s0); s1 = fmaf(dy, (float)rv[1], s1);
        s2 = fmaf(dz, (float)rv[2], s2); s3 = fmaf(dw, (float)rv[3], s3);
    }
    drk[h * RLEN + jj] = (s0 + s1) + (s2 + s3);
}

// ---------------------------------------------------------------------------
// Banded rel logits via f16 MFMA; rk band staged DIRECT via global_load_lds
// (source pre-swizzled for KSWZ). Output SHIFTED+TRANSPOSED f16:
// relbT[bh][bi][jl][r], jl = ccg-127+r.
// ---------------------------------------------------------------------------
__global__ __launch_bounds__(256) void relb_mfma(
    const _Float16* __restrict__ qkvh, const _Float16* __restrict__ rkh,
    const float* __restrict__ rb, _Float16* __restrict__ relbT)
{
    __shared__ _Float16 sR[8192];   // 128 band rows x 64 d
    const int ct = blockIdx.x, bi = blockIdx.y, bh = blockIdx.z;
    const int b = bh >> 3, h = bh & 7;
    const int i0 = bi * 128;
    const int c0 = (bi == 0) ? 0 : (bi - 1) * 128;
    const int jjbase = c0 - i0 - 127 + (NSEQ - 1) + ct * 128;  // in [1280,1920)
    const int t = threadIdx.x;
    const int wave = t >> 6, lane = t & 63;
    const int fr = lane & 15, quad = lane >> 4;

    // ---- stage rk band: direct global->LDS, pre-swizzled source ----
    {
        const _Float16* Rg = rkh + (size_t)jjbase * RKLD + h * 64;
#pragma unroll
        for (int it = 0; it < 4; ++it) {
            int cidx = it * 256 + t;           // 0..1023 chunk id
            int row = cidx >> 3, slot = cidx & 7;
            int gch = slot ^ (row & 7);
            cp16(Rg + (size_t)row * RKLD + gch * 8,
                 &sR[it * 2048 + wave * 512]);
        }
    }
    // ---- Q + rel-pos-bias fragments (f16 source) ----
    f16x8 qf[2][2];
    {
        const _Float16* Qg = qkvh + ((size_t)(b * NSEQ + i0)) * HD3 + h * 64;
#pragma unroll
        for (int ti = 0; ti < 2; ++ti)
#pragma unroll
            for (int kc = 0; kc < 2; ++kc) {
                int m = wave * 32 + ti * 16 + fr;
                int k8 = kc * 32 + quad * 8;
                f16x8 qv = *(const f16x8*)(Qg + (size_t)m * HD3 + k8);
                const float* cp = rb + h * 64 + k8;
                _Float16 hx[8];
#pragma unroll
                for (int u = 0; u < 8; ++u)
                    hx[u] = (_Float16)((float)qv[u] + cp[u]);
                qf[ti][kc] = *(f16x8*)hx;
            }
    }
    __syncthreads();

    // ---- S = (Q+rpb) · rk^T ----
    f32x4 sacc[2][8];
#pragma unroll
    for (int i = 0; i < 2; ++i)
#pragma unroll
        for (int j = 0; j < 8; ++j)
#pragma unroll
            for (int c = 0; c < 4; ++c) sacc[i][j][c] = 0.f;

#pragma unroll
    for (int kc = 0; kc < 2; ++kc) {
        f16x8 bv[8];
#pragma unroll
        for (int tj = 0; tj < 8; ++tj)
            bv[tj] = *(const f16x8*)&sR[KSWZ(tj * 16 + fr, kc * 32 + quad * 8)];
#pragma unroll
        for (int ti = 0; ti < 2; ++ti)
#pragma unroll
            for (int tj = 0; tj < 8; ++tj)
                sacc[ti][tj] = __builtin_amdgcn_mfma_f32_16x16x32_f16(
                    qf[ti][kc], bv[tj], sacc[ti][tj], 0, 0, 0);
    }

    // ---- shifted scatter-store to relbT ----
    size_t bb_ = ((size_t)bh * NB + bi) * 512;
#pragma unroll
    for (int ti = 0; ti < 2; ++ti) {
        int mr = wave * 32 + ti * 16 + quad * 4;
#pragma unroll
        for (int tj = 0; tj < 8; ++tj) {
            int ccg = ct * 128 + tj * 16 + fr;
#pragma unroll
            for (int reg = 0; reg < 4; ++reg) {
                int r = mr + reg;
                int jl = ccg - 127 + r;            // < 512 always
                if (jl >= 0)
                    relbT[(bb_ + jl) * 128 + r] = (_Float16)sacc[ti][tj][reg];
            }
        }
    }
}

// ---------------------------------------------------------------------------
// FLASH attention: one block per (bi, bh) loops over the 2-3 local K/V tiles,
// accumulating O/l in registers (softmax is UNNORMALIZED — no running max —
// so cross-tile accumulation needs no rescale). Replaces the 3-slice O_part
// round-trip (37.8 MB) + norm_merge. Normalizes in-kernel, writes aoh f16.
// Global rows (i<4, bi==0) are overwritten later by gfix.
// bi>=2 blocks fold in the 4 global columns (p_g/vg/lg in LDS).
// ---------------------------------------------------------------------------
__global__ __launch_bounds__(256) void attn_flash(
    const _Float16* __restrict__ qkvh, const _Float16* __restrict__ relbT,
    const _Float16* __restrict__ rkh, const float* __restrict__ drk,
    const float* __restrict__ cb, _Float16* __restrict__ aoh)
{
    __shared__ unsigned short sKP[16384];   // K f16 [0:8192] -> P bf16 (PSWZ)
    __shared__ unsigned short sVt[64 * VSTR];  // V^T bf16 [d][VSTR]
    __shared__ float p_g[128 * 4];          // gcols p per (row, j)
    __shared__ __align__(16) float vg[4 * 64];  // global V rows 0..3
    __shared__ float lg[128];               // gcols l per row
    __shared__ float lrow[128];             // local l per row (post-reduce)
    const int bi = blockIdx.x, bh = blockIdx.y;
    const int b = bh >> 3, h = bh & 7;
    const int i0 = bi * 128;
    const int c0 = (bi == 0) ? 0 : (bi - 1) * 128;
    const int c1 = (bi == NB - 1) ? NSEQ : (bi + 2) * 128;
    const int nt = (c1 - c0) >> 7;          // 2 or 3 tiles
    const int t = threadIdx.x;
    const int wave = t >> 6, lane = t & 63;
    const int fr = lane & 15, quad = lane >> 4;
    const bool do_g = (bi >= 2);
    const unsigned short* Vall = (const unsigned short*)qkvh;

    // ---- fused global-column (cols 0..3) contribution, once per block ----
    if (do_g) {
        if (t < 128) {
            const int r = t;
            const int i = i0 + r;
            const int jjb = NSEQ - 1 - i;       // jj for j=0; j adds +j
            const _Float16* qrow = qkvh + (size_t)(b * NSEQ + i) * HD3 + h * 64;
            const _Float16* krow = qkvh + (size_t)(b * NSEQ) * HD3 + 512 + h * 64;
            const _Float16* rrow = rkh + (size_t)jjb * RKLD + h * 64;
            float s[4] = {0.f, 0.f, 0.f, 0.f};
#pragma unroll
            for (int d4 = 0; d4 < 16; ++d4) {
                f16x4 qv = *(const f16x4*)(qrow + d4 * 4);
                float4 cv = *(const float4*)(cb + h * 64 + d4 * 4);
                float q0 = (float)qv[0] + cv.x, q1 = (float)qv[1] + cv.y;
                float q2 = (float)qv[2] + cv.z, q3 = (float)qv[3] + cv.w;
#pragma unroll
                for (int j = 0; j < 4; ++j) {
                    f16x4 kv = *(const f16x4*)(krow + (size_t)j * HD3 + d4 * 4);
                    f16x4 rv = *(const f16x4*)(rrow + (size_t)j * RKLD + d4 * 4);
                    s[j] = fmaf(q0, (float)kv[0] + (float)rv[0], s[j]);
                    s[j] = fmaf(q1, (float)kv[1] + (float)rv[1], s[j]);
                    s[j] = fmaf(q2, (float)kv[2] + (float)rv[2], s[j]);
                    s[j] = fmaf(q3, (float)kv[3] + (float)rv[3], s[j]);
                }
            }
            float l = 0.f;
#pragma unroll
            for (int j = 0; j < 4; ++j) {
                float p = __expf(s[j] + drk[h * RLEN + jjb + j]);
                p_g[r * 4 + j] = p;
                l += p;
            }
            lg[r] = l;
        } else {
            const unsigned short* Vg0 = Vall + (size_t)(b * NSEQ) * HD3
                                        + 1024 + h * 64;
            int u = (t - 128) * 2;
#pragma unroll
            for (int w = 0; w < 2; ++w) {
                int idx = u + w;               // j*64 + d
                vg[idx] = bf2f(Vg0[(size_t)(idx >> 6) * HD3 + (idx & 63)]);
            }
        }
    }
    // ---- Q fragments in registers (f16 q + content bias), once ----
    f16x8 qf[2][2];
    {
        const _Float16* Qg = qkvh + ((size_t)(b * NSEQ + i0)) * HD3 + h * 64;
#pragma unroll
        for (int ti = 0; ti < 2; ++ti)
#pragma unroll
            for (int kc = 0; kc < 2; ++kc) {
                int m = wave * 32 + ti * 16 + fr;
                int k8 = kc * 32 + quad * 8;
                f16x8 qv = *(const f16x8*)(Qg + (size_t)m * HD3 + k8);
                const float* cp = cb + h * 64 + k8;
                _Float16 hx[8];
#pragma unroll
                for (int u = 0; u < 8; ++u)
                    hx[u] = (_Float16)((float)qv[u] + cp[u]);
                qf[ti][kc] = *(f16x8*)hx;
            }
    }

    // ---- persistent accumulators across tiles ----
    f32x4 oacc[4][2];
#pragma unroll
    for (int i = 0; i < 4; ++i)
#pragma unroll
        for (int j = 0; j < 2; ++j)
#pragma unroll
            for (int c = 0; c < 4; ++c) oacc[i][j][c] = 0.f;
    float lsum[2][4] = {{0.f, 0.f, 0.f, 0.f}, {0.f, 0.f, 0.f, 0.f}};

    for (int ct = 0; ct < nt; ++ct) {
        const int ctile = c0 + ct * 128;
        // ---- stage K: direct global->LDS, pre-swizzled source (f16 bits) ----
        {
            const _Float16* Kg = qkvh + ((size_t)(b * NSEQ + ctile)) * HD3
                                 + 512 + h * 64;
#pragma unroll
            for (int it = 0; it < 4; ++it) {
                int cidx = it * 256 + t;           // 0..1023
                int row = cidx >> 3, slot = cidx & 7;
                int gch = slot ^ (row & 7);
                cp16(Kg + (size_t)row * HD3 + gch * 8,
                     (unsigned short*)&sKP[it * 2048 + wave * 512]);
            }
        }
        // ---- stage V transposed (bf16 bits, pure moves, [d][VSTR]) ----
        {
            const unsigned short* Vg = Vall + ((size_t)(b * NSEQ + ctile)) * HD3
                                       + 1024 + h * 64;
#pragma unroll
            for (int it = 0; it < 2; ++it) {
                int lin = it * 256 + t;            // 0..511
                int r4 = (lin >> 4) * 4, d4 = (lin & 15) * 4;
                ushort4 v0 = *(const ushort4*)(Vg + (size_t)(r4 + 0) * HD3 + d4);
                ushort4 v1 = *(const ushort4*)(Vg + (size_t)(r4 + 1) * HD3 + d4);
                ushort4 v2 = *(const ushort4*)(Vg + (size_t)(r4 + 2) * HD3 + d4);
                ushort4 v3 = *(const ushort4*)(Vg + (size_t)(r4 + 3) * HD3 + d4);
                const unsigned short* p0 = (const unsigned short*)&v0;
                const unsigned short* p1 = (const unsigned short*)&v1;
                const unsigned short* p2 = (const unsigned short*)&v2;
                const unsigned short* p3 = (const unsigned short*)&v3;
#pragma unroll
                for (int dd = 0; dd < 4; ++dd) {
                    ushort4 hh;
                    hh.x = p0[dd]; hh.y = p1[dd]; hh.z = p2[dd]; hh.w = p3[dd];
                    *(ushort4*)&sVt[(d4 + dd) * VSTR + r4] = hh;
                }
            }
        }
        __syncthreads();

        // ---- S = Q K^T (f16 MFMA, f32 accum) ----
        f32x4 sacc[2][8];
#pragma unroll
        for (int i = 0; i < 2; ++i)
#pragma unroll
            for (int j = 0; j < 8; ++j)
#pragma unroll
                for (int c = 0; c < 4; ++c) sacc[i][j][c] = 0.f;

#pragma unroll
        for (int kc = 0; kc < 2; ++kc) {
            f16x8 bv[8];
#pragma unroll
            for (int tj = 0; tj < 8; ++tj)
                bv[tj] = *(const f16x8*)&sKP[KSWZ(tj * 16 + fr,
                                                  kc * 32 + quad * 8)];
#pragma unroll
            for (int ti = 0; ti < 2; ++ti)
#pragma unroll
                for (int tj = 0; tj < 8; ++tj)
                    sacc[ti][tj] = __builtin_amdgcn_mfma_f32_16x16x32_f16(
                        qf[ti][kc], bv[tj], sacc[ti][tj], 0, 0, 0);
        }
        __syncthreads();   // all waves done reading K before P overwrites it

        // ---- rel + exp -> P (bf16, PSWZ); row-sums accumulate ----
        const _Float16* relbase = relbT
            + (((size_t)bh * NB + bi) * 512 + ct * 128) * 128;
#pragma unroll
        for (int ti = 0; ti < 2; ++ti) {
            int mr = wave * 32 + ti * 16 + quad * 4;
#pragma unroll
            for (int tj = 0; tj < 8; ++tj) {
                int j = tj * 16 + fr;
                f16x4 rl = *(const f16x4*)&relbase[(size_t)j * 128 + mr];
#pragma unroll
                for (int reg = 0; reg < 4; ++reg) {
                    int r = mr + reg;
                    float p = __expf(sacc[ti][tj][reg] + (float)rl[reg]);
                    unsigned short pb = f2bf(p);
                    lsum[ti][reg] += bf2f(pb);     // l consistent with bf16 P
                    sKP[PSWZ(r, j)] = pb;
                }
            }
        }
        // (no barrier: each wave consumes only its own P rows below)

        // ---- O^T += Vt x P^T (bf16 MFMA) ----
#pragma unroll
        for (int kc = 0; kc < 4; ++kc) {
            bf16x8 pbv[2];
#pragma unroll
            for (int rt2 = 0; rt2 < 2; ++rt2) {
                int r = (wave * 2 + rt2) * 16 + fr;
                pbv[rt2] = *(const bf16x8*)&sKP[PSWZ(r, kc * 32 + quad * 8)];
            }
#pragma unroll
            for (int dt = 0; dt < 4; ++dt) {
                bf16x8 av = *(const bf16x8*)&sVt[(dt * 16 + fr) * VSTR
                                                 + kc * 32 + quad * 8];
#pragma unroll
                for (int rt2 = 0; rt2 < 2; ++rt2)
                    oacc[dt][rt2] = __builtin_amdgcn_mfma_f32_16x16x32_bf16(
                        av, pbv[rt2], oacc[dt][rt2], 0, 0, 0);
            }
        }
        __syncthreads();   // before next tile's staging overwrites sKP/sVt
    }

    // ---- reduce l across fr lanes; publish per-row l in LDS ----
#pragma unroll
    for (int m2 = 1; m2 < 16; m2 <<= 1)
#pragma unroll
        for (int ti = 0; ti < 2; ++ti)
#pragma unroll
            for (int reg = 0; reg < 4; ++reg)
                lsum[ti][reg] += __shfl_xor(lsum[ti][reg], m2, 64);
    if (fr == 0) {
#pragma unroll
        for (int ti = 0; ti < 2; ++ti) {
            int mr = wave * 32 + ti * 16 + quad * 4;
#pragma unroll
            for (int reg = 0; reg < 4; ++reg)
                lrow[mr + reg] = lsum[ti][reg];
        }
    }
    __syncthreads();

    // ---- normalize + (gcols) + write aoh f16 ----
#pragma unroll
    for (int rt2 = 0; rt2 < 2; ++rt2) {
        int r = (wave * 2 + rt2) * 16 + fr;
        float l = lrow[r] + (do_g ? lg[r] : 0.f);
        float linv = 1.f / l;
        float pg0 = 0.f, pg1 = 0.f, pg2 = 0.f, pg3 = 0.f;
        if (do_g) {
            pg0 = p_g[r * 4 + 0]; pg1 = p_g[r * 4 + 1];
            pg2 = p_g[r * 4 + 2]; pg3 = p_g[r * 4 + 3];
        }
        _Float16* arow = aoh + ((size_t)(b * NSEQ + i0 + r)) * 512 + h * 64;
#pragma unroll
        for (int dt = 0; dt < 4; ++dt) {
            int d = dt * 16 + quad * 4;
            float4 ov = make_float4(oacc[dt][rt2][0], oacc[dt][rt2][1],
                                    oacc[dt][rt2][2], oacc[dt][rt2][3]);
            if (do_g) {
                float4 v0 = *(const float4*)&vg[0 * 64 + d];
                float4 v1 = *(const float4*)&vg[1 * 64 + d];
                float4 v2 = *(const float4*)&vg[2 * 64 + d];
                float4 v3 = *(const float4*)&vg[3 * 64 + d];
                ov.x += pg0 * v0.x + pg1 * v1.x + pg2 * v2.x + pg3 * v3.x;
                ov.y += pg0 * v0.y + pg1 * v1.y + pg2 * v2.y + pg3 * v3.y;
                ov.z += pg0 * v0.z + pg1 * v1.z + pg2 * v2.z + pg3 * v3.z;
                ov.w += pg0 * v0.w + pg1 * v1.w + pg2 * v2.w + pg3 * v3.w;
            }
            union { _Float16 h[4]; ushort4 u; } cc;
            cc.h[0] = (_Float16)(ov.x * linv); cc.h[1] = (_Float16)(ov.y * linv);
            cc.h[2] = (_Float16)(ov.z * linv); cc.h[3] = (_Float16)(ov.w * linv);
            *(ushort4*)(arow + d) = cc.u;
        }
    }
}

// ---------------------------------------------------------------------------
// Global-ROW attention partials: grid (12 col-chunks, 64 bhi), 256 thr.
// ---------------------------------------------------------------------------
__global__ __launch_bounds__(256) void grows_part(
    const _Float16* __restrict__ qkvh, const _Float16* __restrict__ rkh,
    const float* __restrict__ drk, const float* __restrict__ cb,
    float* __restrict__ g_O, float* __restrict__ g_l)
{
    __shared__ float qc_s[64];
    __shared__ float p_s[128];
    __shared__ float obuf[4][64];
    __shared__ float lred[2];
    const int chunk = blockIdx.x;        // 0..11
    const int bhi = blockIdx.y;          // 0..63
    const int i = bhi & 3, h = (bhi >> 2) & 7, b = bhi >> 5;
    const int t = threadIdx.x;
    const int c0 = chunk * 128;
    if (t < 64)
        qc_s[t] = (float)qkvh[(size_t)(b * NSEQ + i) * HD3 + h * 64 + t]
                  + cb[h * 64 + t];
    __syncthreads();
    if (t < 128) {
        int j = c0 + t;
        const _Float16* krow = qkvh + (size_t)(b * NSEQ + j) * HD3 + 512 + h * 64;
        int jj = j - i + (NSEQ - 1);
        const _Float16* rrow = rkh + (size_t)jj * RKLD + h * 64;
        float s0 = 0, s1 = 0, s2 = 0, s3 = 0;
#pragma unroll
        for (int d4 = 0; d4 < 16; ++d4) {
            f16x4 kv = *(const f16x4*)(krow + d4 * 4);
            f16x4 rv = *(const f16x4*)(rrow + d4 * 4);
            float4 qv = *(const float4*)(&qc_s[d4 * 4]);
            s0 = fmaf(qv.x, (float)kv[0] + (float)rv[0], s0);
            s1 = fmaf(qv.y, (float)kv[1] + (float)rv[1], s1);
            s2 = fmaf(qv.z, (float)kv[2] + (float)rv[2], s2);
            s3 = fmaf(qv.w, (float)kv[3] + (float)rv[3], s3);
        }
        float p = __expf((s0 + s1) + (s2 + s3) + drk[h * RLEN + jj]);
        p_s[t] = p;
        float ls = p;
#pragma unroll
        for (int off = 32; off > 0; off >>= 1)
            ls += __shfl_down(ls, off, 64);
        if ((t & 63) == 0) lred[t >> 6] = ls;
    }
    __syncthreads();
    {
        const int d = t & 63, g = t >> 6;
        float a0 = 0, a1 = 0;
        const unsigned short* vbase = (const unsigned short*)qkvh
            + (size_t)(b * NSEQ + c0 + g * 32) * HD3 + 1024 + h * 64 + d;
#pragma unroll
        for (int j2 = 0; j2 < 32; j2 += 2) {
            a0 = fmaf(p_s[g * 32 + j2],     bf2f(vbase[(size_t)j2 * HD3]),       a0);
            a1 = fmaf(p_s[g * 32 + j2 + 1], bf2f(vbase[(size_t)(j2 + 1) * HD3]), a1);
        }
        obuf[g][d] = a0 + a1;
    }
    __syncthreads();
    if (t < 64) {
        float o = (obuf[0][t] + obuf[1][t]) + (obuf[2][t] + obuf[3][t]);
        g_O[((size_t)chunk * 64 + bhi) * 64 + t] = o;
        if (t == 0) g_l[chunk * 64 + bhi] = lred[0] + lred[1];
    }
}

// ---------------------------------------------------------------------------
// Overwrite the 64 global rows (i<4 per b,h) of aoh from grows_part partials.
// grid 16 (=bh), 256 thr: i = t>>6, d = t&63.
// ---------------------------------------------------------------------------
__global__ __launch_bounds__(256) void gfix(
    const float* __restrict__ g_O, const float* __restrict__ g_l,
    _Float16* __restrict__ aoh)
{
    const int bh = blockIdx.x, b = bh >> 3, h = bh & 7;
    const int i = threadIdx.x >> 6, d = threadIdx.x & 63;
    const int bhi = bh * 4 + i;
    float o = 0.f, l = 0.f;
#pragma unroll
    for (int c = 0; c < 12; ++c) {
        o += g_O[((size_t)c * 64 + bhi) * 64 + d];
        l += g_l[c * 64 + bhi];
    }
    aoh[((size_t)(b * NSEQ + i)) * 512 + h * 64 + d] = (_Float16)(o / l);
}

// ---------------------------------------------------------------------------
extern "C" void kernel_launch(void* const* d_in, const int* in_sizes, int n_in,
                              void* d_out, int out_size, void* d_ws, size_t ws_size,
                              hipStream_t stream)
{
    const float* x    = (const float*)d_in[0];
    const float* Wq   = (const float*)d_in[1];
    const float* Wk   = (const float*)d_in[2];
    const float* Wv   = (const float*)d_in[3];
    const float* Wrel = (const float*)d_in[4];
    const float* cb   = (const float*)d_in[5];
    const float* rb   = (const float*)d_in[6];
    const float* Wo   = (const float*)d_in[7];
    const float* bo   = (const float*)d_in[8];
    const float* pe   = (const float*)d_in[9];
    float* out = (float*)d_out;

    float* ws = (float*)d_ws;
    _Float16* qkvh = (_Float16*)ws;                      // [3072][1536] Q,K f16 | V bf16
    _Float16* rkh  = (_Float16*)(ws + 2359296);          // [3072][512] f16 (row 3071 scratch)
    float* drk   = ws + 3145728;                         // [8][3071] f32
    _Float16* aoh = (_Float16*)(ws + 3170304);           // [3072][512] f16
    _Float16* woh = (_Float16*)(ws + 3956736);           // WoT [1536][512] f16
    float* R = ws + 4349952;                             // aliased region
    _Float16* relbT = (_Float16*)R;                          // [16][12][512][128] f16
    _Float16* xh  = (_Float16*)R;                            // dead before relbT written
    _Float16* wqh = (_Float16*)(R + 2359296);                // WqkvT [1536][1536] f16
    float* g_O = R + 6291456;                            // [12][64][64] f32 (after relbT)
    float* g_l = R + 6340608;                            // [12][64] f32
    _Float16* peh   = (_Float16*)(ws + 15483648);        // [3072][192] f16 (row 3071 scratch)
    _Float16* wrelT = (_Float16*)(ws + 15778560);        // WrelT [512][192] f16

    dim3 blk(256);
    split2_f16<<<5184, blk, 0, stream>>>(x, xh, pe, peh);
    wsplit_all<<<dim3(8, 24, 5), blk, 0, stream>>>(Wq, Wk, Wv, Wo, Wrel,
                                                   wqh, woh, wrelT);
    gemm_f16k<<<dim3(24, 48), blk, 0, stream>>>(xh, wqh, nullptr, qkvh,
                                                3072, 1536, 1536, 1);
    gemm_f16k<<<dim3(8, 48), blk, 0, stream>>>(peh, wrelT, nullptr, rkh,
                                               3072, 512, 192, 2);
    drk_kernel<<<96, blk, 0, stream>>>(rkh, cb, rb, drk);
    relb_mfma<<<dim3(4, 12, 16), blk, 0, stream>>>(qkvh, rkh, rb, relbT);
    attn_flash<<<dim3(12, 16), blk, 0, stream>>>(qkvh, relbT, rkh, drk, cb, aoh);
    grows_part<<<dim3(12, 64), blk, 0, stream>>>(qkvh, rkh, drk, cb, g_O, g_l);
    gfix<<<16, blk, 0, stream>>>(g_O, g_l, aoh);
    gemm_f16k<<<dim3(24, 48), blk, 0, stream>>>(aoh, woh, bo, out,
                                                3072, 1536, 512, 0);
}

// Round 8
// 224.102 us; speedup vs baseline: 1.0313x; 1.0313x over previous
//
#include <hip/hip_runtime.h>
#include <math.h>

#define NSEQ 1536
#define HD3  1536      // fused qkv row stride
#define RKLD 512       // rel_k row stride
#define RLEN 3071
#define NB   12

typedef __attribute__((ext_vector_type(8))) short bf16x8;
typedef __attribute__((ext_vector_type(4))) float f32x4;
typedef _Float16 f16x8 __attribute__((ext_vector_type(8)));
typedef _Float16 f16x4 __attribute__((ext_vector_type(4)));

__device__ __forceinline__ unsigned short f2bf(float f) {
    union { float f; unsigned u; } v; v.f = f;
    unsigned r = v.u + 0x7fffu + ((v.u >> 16) & 1u);
    return (unsigned short)(r >> 16);
}
__device__ __forceinline__ float bf2f(unsigned short s) {
    union { unsigned u; float f; } v; v.u = ((unsigned)s) << 16;
    return v.f;
}
__device__ __forceinline__ unsigned short f2h(float f) {
    union { _Float16 h; unsigned short u; } c; c.h = (_Float16)f; return c.u;
}
__device__ __forceinline__ void cp16(const void* g, void* l) {
    __builtin_amdgcn_global_load_lds(
        (const __attribute__((address_space(1))) void*)g,
        (__attribute__((address_space(3))) void*)l, 16, 0, 0);
}

// LDS swizzles: keep 8-elem chunks contiguous; XOR chunk id with row bits to
// break power-of-2 stride bank conflicts.
#define KSWZ(row, d) ((row) * 64 + (((((d) >> 3) ^ ((row) & 7))) << 3) + ((d) & 7))
#define PSWZ(r, j)   ((r) * 128 + (((((j) >> 3) ^ ((r) & 15))) << 3) + ((j) & 7))
#define VSTR 136     // Vt row stride in elems (272B: 16B-aligned, non-pow2)

// ---------------------------------------------------------------------------
// fp32 -> f16: x (4608 blocks) and pos_embed (576 blocks) in one launch.
// ---------------------------------------------------------------------------
__global__ __launch_bounds__(256) void split2_f16(
    const float* __restrict__ X, _Float16* __restrict__ HX,
    const float* __restrict__ P, _Float16* __restrict__ HP)
{
    const int bid = blockIdx.x;
    const float* src; _Float16* dst; int i;
    if (bid < 4608) {                    // 4608*256 == 1179648 exactly
        i = bid * 256 + threadIdx.x;
        src = X; dst = HX;
    } else {
        i = (bid - 4608) * 256 + threadIdx.x;
        if (i >= 147408) return;         // 3071*192/4
        src = P; dst = HP;
    }
    float4 v = ((const float4*)src)[i];
    union { _Float16 h[4]; ushort4 u; } c;
    c.h[0] = (_Float16)v.x; c.h[1] = (_Float16)v.y;
    c.h[2] = (_Float16)v.z; c.h[3] = (_Float16)v.w;
    ((ushort4*)dst)[i] = c.u;
}

// ---------------------------------------------------------------------------
// Weight transpose (generic): W[K][N] f32 -> T[n_off+N][ldt] f16
// ---------------------------------------------------------------------------
__device__ __forceinline__ void wsplit_body16(
    const float* __restrict__ W, _Float16* __restrict__ T,
    int K, int N, int n_off, int ldt, float scale, int bx, int by)
{
    __shared__ float tile[64][65];
    const int k0 = by * 64, n0 = bx * 64;
    const int t = threadIdx.x;
    const int rr = t >> 4, c4 = (t & 15) * 4;
#pragma unroll
    for (int p = 0; p < 4; ++p) {
        int r = p * 16 + rr;
        float4 v = *(const float4*)(W + (size_t)(k0 + r) * N + n0 + c4);
        tile[r][c4 + 0] = v.x; tile[r][c4 + 1] = v.y;
        tile[r][c4 + 2] = v.z; tile[r][c4 + 3] = v.w;
    }
    __syncthreads();
#pragma unroll
    for (int p = 0; p < 4; ++p) {
        int n = p * 16 + rr;
        union { _Float16 h[4]; ushort4 u; } cc;
        cc.h[0] = (_Float16)(tile[c4 + 0][n] * scale);
        cc.h[1] = (_Float16)(tile[c4 + 1][n] * scale);
        cc.h[2] = (_Float16)(tile[c4 + 2][n] * scale);
        cc.h[3] = (_Float16)(tile[c4 + 3][n] * scale);
        size_t o = (size_t)(n_off + n0 + n) * ldt + k0 + c4;
        *(ushort4*)(T + o) = cc.u;
    }
}

// One launch transposes all five weights: z=0..2 Wq/Wk/Wv, z=3 Wo, z=4 Wrel.
__global__ __launch_bounds__(256) void wsplit_all(
    const float* __restrict__ Wq, const float* __restrict__ Wk,
    const float* __restrict__ Wv, const float* __restrict__ Wo,
    const float* __restrict__ Wrel,
    _Float16* __restrict__ Tqkv, _Float16* __restrict__ To,
    _Float16* __restrict__ Trel)
{
    const int z = blockIdx.z;
    if (z < 3) {
        const float* W = (z == 0) ? Wq : (z == 1) ? Wk : Wv;
        wsplit_body16(W, Tqkv, 1536, 512, z * 512, 1536,
                      (z == 0) ? 0.125f : 1.f, blockIdx.x, blockIdx.y);
    } else if (z == 3) {
        wsplit_body16(Wo, To, 512, 1536, 0, 512, 1.f, blockIdx.y, blockIdx.x);
    } else {
        if (blockIdx.y >= 3) return;   // uniform per block, before any barrier
        wsplit_body16(Wrel, Trel, 192, 512, 0, 192, 1.f, blockIdx.x, blockIdx.y);
    }
}

// ---------------------------------------------------------------------------
// Single-term f16 MFMA GEMM, 64x64 tile, BK=64: C = A·B^T (+bias).
// 2-buffer single-barrier; 32KB LDS; KSWZ; XCD swizzle.
// omode 0: C f32 + bias. omode 1: QKV split store — cols<1024 f16 (Q,K),
// cols>=1024 bf16 (V: must pair with bf16 P in the PV MFMA). omode 2: f16.
// ---------------------------------------------------------------------------
__global__ __launch_bounds__(256) void gemm_f16k(
    const _Float16* __restrict__ A,   // [M][K] f16
    const _Float16* __restrict__ B,   // [N][K] f16 (pre-transposed weight)
    const float* __restrict__ bias, void* __restrict__ C,
    int M, int N, int K, int omode)
{
    __shared__ _Float16 sA[2][4096];    // [buf][64*64]
    __shared__ _Float16 sB[2][4096];
    const int t = threadIdx.x;
    const int wave = t >> 6, lane = t & 63;
    // XCD-aware bijective swizzle (nwg % 8 == 0 for all launches here)
    const int nwg = gridDim.x * gridDim.y;
    const int lin = blockIdx.y * gridDim.x + blockIdx.x;
    const int swz = (lin & 7) * (nwg >> 3) + (lin >> 3);
    const int bx = swz % gridDim.x, by = swz / gridDim.x;
    const int m0 = by * 64, n0 = bx * 64;
    const int wm = (wave >> 1) * 32, wn = (wave & 1) * 32;
    const int fr = lane & 15, quad = lane >> 4;

    f32x4 acc[2][2];
#pragma unroll
    for (int i = 0; i < 2; ++i)
#pragma unroll
        for (int j = 0; j < 2; ++j)
#pragma unroll
            for (int c = 0; c < 4; ++c) acc[i][j][c] = 0.f;

    const int nsteps = K >> 6;

#define STAGE(k0, buf)                                                        \
    {                                                                         \
        _Pragma("unroll")                                                     \
        for (int it = 0; it < 2; ++it) {                                      \
            int cidx = it * 256 + t;                                          \
            int row = cidx >> 3, slot = cidx & 7;                             \
            int gch = slot ^ (row & 7);                                       \
            size_t goA = (size_t)(m0 + row) * K + (k0) + gch * 8;             \
            size_t goB = (size_t)(n0 + row) * K + (k0) + gch * 8;             \
            cp16(A + goA, &sA[buf][it * 2048 + wave * 512]);                  \
            cp16(B + goB, &sB[buf][it * 2048 + wave * 512]);                  \
        }                                                                     \
    }

    STAGE(0, 0);
    for (int s = 0; s < nsteps; ++s) {
        const int buf = s & 1;
        __syncthreads();
        if (s + 1 < nsteps) STAGE((s + 1) * 64, buf ^ 1);

        f16x8 fa[2][2], fb[2][2];
#pragma unroll
        for (int ti = 0; ti < 2; ++ti)
#pragma unroll
            for (int kc = 0; kc < 2; ++kc) {
                fa[ti][kc] = *(const f16x8*)&sA[buf][KSWZ(wm + ti * 16 + fr,
                                                          kc * 32 + quad * 8)];
                fb[ti][kc] = *(const f16x8*)&sB[buf][KSWZ(wn + ti * 16 + fr,
                                                          kc * 32 + quad * 8)];
            }
#pragma unroll
        for (int ti = 0; ti < 2; ++ti)
#pragma unroll
            for (int tj = 0; tj < 2; ++tj)
#pragma unroll
                for (int kc = 0; kc < 2; ++kc)
                    acc[ti][tj] = __builtin_amdgcn_mfma_f32_16x16x32_f16(
                        fa[ti][kc], fb[tj][kc], acc[ti][tj], 0, 0, 0);
    }
#undef STAGE

    if (omode == 0) {
        float* Cf = (float*)C;
#pragma unroll
        for (int ti = 0; ti < 2; ++ti) {
            int rowb = m0 + wm + ti * 16 + quad * 4;
#pragma unroll
            for (int tj = 0; tj < 2; ++tj) {
                int col = n0 + wn + tj * 16 + fr;
                float bb = bias ? bias[col] : 0.f;
#pragma unroll
                for (int j2 = 0; j2 < 4; ++j2)
                    Cf[(size_t)(rowb + j2) * N + col] = acc[ti][tj][j2] + bb;
            }
        }
    } else {
        unsigned short* Cu = (unsigned short*)C;
        const bool vb = (omode == 1) && (n0 >= 1024);   // V region -> bf16
#pragma unroll
        for (int ti = 0; ti < 2; ++ti) {
            int rowb = m0 + wm + ti * 16 + quad * 4;
#pragma unroll
            for (int tj = 0; tj < 2; ++tj) {
                int col = n0 + wn + tj * 16 + fr;
#pragma unroll
                for (int j2 = 0; j2 < 4; ++j2) {
                    float v = acc[ti][tj][j2];
                    Cu[(size_t)(rowb + j2) * N + col] = vb ? f2bf(v) : f2h(v);
                }
            }
        }
    }
}

// ---------------------------------------------------------------------------
// drk[h][jj] = sum_d (rpb[h,d]-rcb[h,d]) * rk[jj, h*64+d]   (rk f16)
// ---------------------------------------------------------------------------
__global__ __launch_bounds__(256) void drk_kernel(
    const _Float16* __restrict__ rkh, const float* __restrict__ cb,
    const float* __restrict__ rb, float* __restrict__ drk)
{
    int idx = blockIdx.x * 256 + threadIdx.x;
    if (idx >= 8 * RLEN) return;
    int jj = idx >> 3, h = idx & 7;
    const _Float16* rrow = rkh + (size_t)jj * RKLD + h * 64;
    float s0 = 0, s1 = 0, s2 = 0, s3 = 0;
#pragma unroll
    for (int d4 = 0; d4 < 16; ++d4) {
        f16x4 rv = *(const f16x4*)(rrow + d4 * 4);
        float dx = rb[h * 64 + d4 * 4 + 0] - cb[h * 64 + d4 * 4 + 0];
        float dy = rb[h * 64 + d4 * 4 + 1] - cb[h * 64 + d4 * 4 + 1];
        float dz = rb[h * 64 + d4 * 4 + 2] - cb[h * 64 + d4 * 4 + 2];
        float dw = rb[h * 64 + d4 * 4 + 3] - cb[h * 64 + d4 * 4 + 3];
        s0 = fmaf(dx, (float)rv[0], s0); s1 = fmaf(dy, (float)rv[1], s1);
        s2 = fmaf(dz, (float)rv[2], s2); s3 = fmaf(dw, (float)rv[3], s3);
    }
    drk[h * RLEN + jj] = (s0 + s1) + (s2 + s3);
}

// ---------------------------------------------------------------------------
// Banded rel logits via f16 MFMA; rk band staged DIRECT via global_load_lds
// (source pre-swizzled for KSWZ). Output SHIFTED+TRANSPOSED f16:
// relbT[bh][bi][jl][r], jl = ccg-127+r.
// ---------------------------------------------------------------------------
__global__ __launch_bounds__(256) void relb_mfma(
    const _Float16* __restrict__ qkvh, const _Float16* __restrict__ rkh,
    const float* __restrict__ rb, _Float16* __restrict__ relbT)
{
    __shared__ _Float16 sR[8192];   // 128 band rows x 64 d
    const int ct = blockIdx.x, bi = blockIdx.y, bh = blockIdx.z;
    const int b = bh >> 3, h = bh & 7;
    const int i0 = bi * 128;
    const int c0 = (bi == 0) ? 0 : (bi - 1) * 128;
    const int jjbase = c0 - i0 - 127 + (NSEQ - 1) + ct * 128;  // in [1280,1920)
    const int t = threadIdx.x;
    const int wave = t >> 6, lane = t & 63;
    const int fr = lane & 15, quad = lane >> 4;

    // ---- stage rk band: direct global->LDS, pre-swizzled source ----
    {
        const _Float16* Rg = rkh + (size_t)jjbase * RKLD + h * 64;
#pragma unroll
        for (int it = 0; it < 4; ++it) {
            int cidx = it * 256 + t;           // 0..1023 chunk id
            int row = cidx >> 3, slot = cidx & 7;
            int gch = slot ^ (row & 7);
            cp16(Rg + (size_t)row * RKLD + gch * 8,
                 &sR[it * 2048 + wave * 512]);
        }
    }
    // ---- Q + rel-pos-bias fragments (f16 source) ----
    f16x8 qf[2][2];
    {
        const _Float16* Qg = qkvh + ((size_t)(b * NSEQ + i0)) * HD3 + h * 64;
#pragma unroll
        for (int ti = 0; ti < 2; ++ti)
#pragma unroll
            for (int kc = 0; kc < 2; ++kc) {
                int m = wave * 32 + ti * 16 + fr;
                int k8 = kc * 32 + quad * 8;
                f16x8 qv = *(const f16x8*)(Qg + (size_t)m * HD3 + k8);
                const float* cp = rb + h * 64 + k8;
                _Float16 hx[8];
#pragma unroll
                for (int u = 0; u < 8; ++u)
                    hx[u] = (_Float16)((float)qv[u] + cp[u]);
                qf[ti][kc] = *(f16x8*)hx;
            }
    }
    __syncthreads();

    // ---- S = (Q+rpb) · rk^T ----
    f32x4 sacc[2][8];
#pragma unroll
    for (int i = 0; i < 2; ++i)
#pragma unroll
        for (int j = 0; j < 8; ++j)
#pragma unroll
            for (int c = 0; c < 4; ++c) sacc[i][j][c] = 0.f;

#pragma unroll
    for (int kc = 0; kc < 2; ++kc) {
        f16x8 bv[8];
#pragma unroll
        for (int tj = 0; tj < 8; ++tj)
            bv[tj] = *(const f16x8*)&sR[KSWZ(tj * 16 + fr, kc * 32 + quad * 8)];
#pragma unroll
        for (int ti = 0; ti < 2; ++ti)
#pragma unroll
            for (int tj = 0; tj < 8; ++tj)
                sacc[ti][tj] = __builtin_amdgcn_mfma_f32_16x16x32_f16(
                    qf[ti][kc], bv[tj], sacc[ti][tj], 0, 0, 0);
    }

    // ---- shifted scatter-store to relbT ----
    size_t bb_ = ((size_t)bh * NB + bi) * 512;
#pragma unroll
    for (int ti = 0; ti < 2; ++ti) {
        int mr = wave * 32 + ti * 16 + quad * 4;
#pragma unroll
        for (int tj = 0; tj < 8; ++tj) {
            int ccg = ct * 128 + tj * 16 + fr;
#pragma unroll
            for (int reg = 0; reg < 4; ++reg) {
                int r = mr + reg;
                int jl = ccg - 127 + r;            // < 512 always
                if (jl >= 0)
                    relbT[(bb_ + jl) * 128 + r] = (_Float16)sacc[ti][tj][reg];
            }
        }
    }
}

// ---------------------------------------------------------------------------
// FLASH attention, 64-ROW Q blocks (R8): grid (bi 12, bh 16, qz 2) = 384
// blocks (1.5/CU vs R7's 192 @0.75 — R7's regression was occupancy, not
// traffic). Each block loops its 2-3 local K/V tiles, accumulating O/l in
// registers (unnormalized softmax — no rescale). K staging duplicated per
// qz half (L2-hot, ~1us). LDS ~35KB: K(16K) and P(64x128,16K) share sKP.
// Global rows (i<4) overwritten later by gfix. bi>=2 folds in 4 gcols.
// ---------------------------------------------------------------------------
__global__ __launch_bounds__(256) void attn_flash(
    const _Float16* __restrict__ qkvh, const _Float16* __restrict__ relbT,
    const _Float16* __restrict__ rkh, const float* __restrict__ drk,
    const float* __restrict__ cb, _Float16* __restrict__ aoh)
{
    __shared__ unsigned short sKP[8192];    // K f16 (128x64) -> P bf16 (64x128)
    __shared__ unsigned short sVt[64 * VSTR];  // V^T bf16 [d][VSTR]
    __shared__ float p_g[64 * 4];           // gcols p per (row, j)
    __shared__ __align__(16) float vg[4 * 64];  // global V rows 0..3
    __shared__ float lg[64];                // gcols l per row
    __shared__ float lrow[64];              // local l per row (post-reduce)
    const int bi = blockIdx.x, bh = blockIdx.y, qz = blockIdx.z;
    const int b = bh >> 3, h = bh & 7;
    const int i0 = bi * 128 + qz * 64;      // this block's 64 Q rows
    const int c0 = (bi == 0) ? 0 : (bi - 1) * 128;
    const int c1 = (bi == NB - 1) ? NSEQ : (bi + 2) * 128;
    const int nt = (c1 - c0) >> 7;          // 2 or 3 tiles
    const int t = threadIdx.x;
    const int wave = t >> 6, lane = t & 63;
    const int fr = lane & 15, quad = lane >> 4;
    const bool do_g = (bi >= 2);
    const unsigned short* Vall = (const unsigned short*)qkvh;

    // ---- fused global-column (cols 0..3) contribution, once per block ----
    if (do_g) {
        if (t < 64) {
            const int r = t;
            const int i = i0 + r;
            const int jjb = NSEQ - 1 - i;       // jj for j=0; j adds +j
            const _Float16* qrow = qkvh + (size_t)(b * NSEQ + i) * HD3 + h * 64;
            const _Float16* krow = qkvh + (size_t)(b * NSEQ) * HD3 + 512 + h * 64;
            const _Float16* rrow = rkh + (size_t)jjb * RKLD + h * 64;
            float s[4] = {0.f, 0.f, 0.f, 0.f};
#pragma unroll
            for (int d4 = 0; d4 < 16; ++d4) {
                f16x4 qv = *(const f16x4*)(qrow + d4 * 4);
                float4 cv = *(const float4*)(cb + h * 64 + d4 * 4);
                float q0 = (float)qv[0] + cv.x, q1 = (float)qv[1] + cv.y;
                float q2 = (float)qv[2] + cv.z, q3 = (float)qv[3] + cv.w;
#pragma unroll
                for (int j = 0; j < 4; ++j) {
                    f16x4 kv = *(const f16x4*)(krow + (size_t)j * HD3 + d4 * 4);
                    f16x4 rv = *(const f16x4*)(rrow + (size_t)j * RKLD + d4 * 4);
                    s[j] = fmaf(q0, (float)kv[0] + (float)rv[0], s[j]);
                    s[j] = fmaf(q1, (float)kv[1] + (float)rv[1], s[j]);
                    s[j] = fmaf(q2, (float)kv[2] + (float)rv[2], s[j]);
                    s[j] = fmaf(q3, (float)kv[3] + (float)rv[3], s[j]);
                }
            }
            float l = 0.f;
#pragma unroll
            for (int j = 0; j < 4; ++j) {
                float p = __expf(s[j] + drk[h * RLEN + jjb + j]);
                p_g[r * 4 + j] = p;
                l += p;
            }
            lg[r] = l;
        } else if (t >= 128) {
            const unsigned short* Vg0 = Vall + (size_t)(b * NSEQ) * HD3
                                        + 1024 + h * 64;
            int u = (t - 128) * 2;
#pragma unroll
            for (int w = 0; w < 2; ++w) {
                int idx = u + w;               // j*64 + d
                vg[idx] = bf2f(Vg0[(size_t)(idx >> 6) * HD3 + (idx & 63)]);
            }
        }
    }
    // ---- Q fragments in registers (f16 q + content bias), once ----
    f16x8 qf[2];
    {
        const _Float16* Qg = qkvh + ((size_t)(b * NSEQ + i0)) * HD3 + h * 64;
        const int m = wave * 16 + fr;
#pragma unroll
        for (int kc = 0; kc < 2; ++kc) {
            int k8 = kc * 32 + quad * 8;
            f16x8 qv = *(const f16x8*)(Qg + (size_t)m * HD3 + k8);
            const float* cp = cb + h * 64 + k8;
            _Float16 hx[8];
#pragma unroll
            for (int u = 0; u < 8; ++u)
                hx[u] = (_Float16)((float)qv[u] + cp[u]);
            qf[kc] = *(f16x8*)hx;
        }
    }

    // ---- persistent accumulators across tiles ----
    f32x4 oacc[4];
#pragma unroll
    for (int i = 0; i < 4; ++i)
#pragma unroll
        for (int c = 0; c < 4; ++c) oacc[i][c] = 0.f;
    float lsum[4] = {0.f, 0.f, 0.f, 0.f};

    for (int ct = 0; ct < nt; ++ct) {
        const int ctile = c0 + ct * 128;
        // ---- stage K: direct global->LDS, pre-swizzled source (f16 bits) ----
        {
            const _Float16* Kg = qkvh + ((size_t)(b * NSEQ + ctile)) * HD3
                                 + 512 + h * 64;
#pragma unroll
            for (int it = 0; it < 4; ++it) {
                int cidx = it * 256 + t;           // 0..1023
                int row = cidx >> 3, slot = cidx & 7;
                int gch = slot ^ (row & 7);
                cp16(Kg + (size_t)row * HD3 + gch * 8,
                     (unsigned short*)&sKP[it * 2048 + wave * 512]);
            }
        }
        // ---- stage V transposed (bf16 bits, pure moves, [d][VSTR]) ----
        {
            const unsigned short* Vg = Vall + ((size_t)(b * NSEQ + ctile)) * HD3
                                       + 1024 + h * 64;
#pragma unroll
            for (int it = 0; it < 2; ++it) {
                int lin = it * 256 + t;            // 0..511
                int r4 = (lin >> 4) * 4, d4 = (lin & 15) * 4;
                ushort4 v0 = *(const ushort4*)(Vg + (size_t)(r4 + 0) * HD3 + d4);
                ushort4 v1 = *(const ushort4*)(Vg + (size_t)(r4 + 1) * HD3 + d4);
                ushort4 v2 = *(const ushort4*)(Vg + (size_t)(r4 + 2) * HD3 + d4);
                ushort4 v3 = *(const ushort4*)(Vg + (size_t)(r4 + 3) * HD3 + d4);
                const unsigned short* p0 = (const unsigned short*)&v0;
                const unsigned short* p1 = (const unsigned short*)&v1;
                const unsigned short* p2 = (const unsigned short*)&v2;
                const unsigned short* p3 = (const unsigned short*)&v3;
#pragma unroll
                for (int dd = 0; dd < 4; ++dd) {
                    ushort4 hh;
                    hh.x = p0[dd]; hh.y = p1[dd]; hh.z = p2[dd]; hh.w = p3[dd];
                    *(ushort4*)&sVt[(d4 + dd) * VSTR + r4] = hh;
                }
            }
        }
        __syncthreads();

        // ---- S = Q K^T (f16 MFMA, f32 accum), 64 rows x 128 cols ----
        f32x4 sacc[8];
#pragma unroll
        for (int j = 0; j < 8; ++j)
#pragma unroll
            for (int c = 0; c < 4; ++c) sacc[j][c] = 0.f;

#pragma unroll
        for (int kc = 0; kc < 2; ++kc) {
            f16x8 bv[8];
#pragma unroll
            for (int tj = 0; tj < 8; ++tj)
                bv[tj] = *(const f16x8*)&sKP[KSWZ(tj * 16 + fr,
                                                  kc * 32 + quad * 8)];
#pragma unroll
            for (int tj = 0; tj < 8; ++tj)
                sacc[tj] = __builtin_amdgcn_mfma_f32_16x16x32_f16(
                    qf[kc], bv[tj], sacc[tj], 0, 0, 0);
        }
        __syncthreads();   // all waves done reading K before P overwrites it

        // ---- rel + exp -> P (bf16, PSWZ, 64x128); row-sums accumulate ----
        const _Float16* relbase = relbT
            + (((size_t)bh * NB + bi) * 512 + ct * 128) * 128;
        {
            int mr = wave * 16 + quad * 4;              // local row in [0,64)
            int mr128 = qz * 64 + mr;                   // row in relbT's 128-space
#pragma unroll
            for (int tj = 0; tj < 8; ++tj) {
                int j = tj * 16 + fr;
                f16x4 rl = *(const f16x4*)&relbase[(size_t)j * 128 + mr128];
#pragma unroll
                for (int reg = 0; reg < 4; ++reg) {
                    int r = mr + reg;
                    float p = __expf(sacc[tj][reg] + (float)rl[reg]);
                    unsigned short pb = f2bf(p);
                    lsum[reg] += bf2f(pb);     // l consistent with bf16 P
                    sKP[PSWZ(r, j)] = pb;
                }
            }
        }
        // (no barrier: each wave consumes only its own 16 P rows below)

        // ---- O^T += Vt x P^T (bf16 MFMA) ----
#pragma unroll
        for (int kc = 0; kc < 4; ++kc) {
            int r = wave * 16 + fr;
            bf16x8 pbv = *(const bf16x8*)&sKP[PSWZ(r, kc * 32 + quad * 8)];
#pragma unroll
            for (int dt = 0; dt < 4; ++dt) {
                bf16x8 av = *(const bf16x8*)&sVt[(dt * 16 + fr) * VSTR
                                                 + kc * 32 + quad * 8];
                oacc[dt] = __builtin_amdgcn_mfma_f32_16x16x32_bf16(
                    av, pbv, oacc[dt], 0, 0, 0);
            }
        }
        __syncthreads();   // before next tile's staging overwrites sKP/sVt
    }

    // ---- reduce l across fr lanes; publish per-row l in LDS ----
#pragma unroll
    for (int m2 = 1; m2 < 16; m2 <<= 1)
#pragma unroll
        for (int reg = 0; reg < 4; ++reg)
            lsum[reg] += __shfl_xor(lsum[reg], m2, 64);
    if (fr == 0) {
        int mr = wave * 16 + quad * 4;
#pragma unroll
        for (int reg = 0; reg < 4; ++reg)
            lrow[mr + reg] = lsum[reg];
    }
    __syncthreads();

    // ---- normalize + (gcols) + write aoh f16 ----
    {
        int r = wave * 16 + fr;
        float l = lrow[r] + (do_g ? lg[r] : 0.f);
        float linv = 1.f / l;
        float pg0 = 0.f, pg1 = 0.f, pg2 = 0.f, pg3 = 0.f;
        if (do_g) {
            pg0 = p_g[r * 4 + 0]; pg1 = p_g[r * 4 + 1];
            pg2 = p_g[r * 4 + 2]; pg3 = p_g[r * 4 + 3];
        }
        _Float16* arow = aoh + ((size_t)(b * NSEQ + i0 + r)) * 512 + h * 64;
#pragma unroll
        for (int dt = 0; dt < 4; ++dt) {
            int d = dt * 16 + quad * 4;
            float4 ov = make_float4(oacc[dt][0], oacc[dt][1],
                                    oacc[dt][2], oacc[dt][3]);
            if (do_g) {
                float4 v0 = *(const float4*)&vg[0 * 64 + d];
                float4 v1 = *(const float4*)&vg[1 * 64 + d];
                float4 v2 = *(const float4*)&vg[2 * 64 + d];
                float4 v3 = *(const float4*)&vg[3 * 64 + d];
                ov.x += pg0 * v0.x + pg1 * v1.x + pg2 * v2.x + pg3 * v3.x;
                ov.y += pg0 * v0.y + pg1 * v1.y + pg2 * v2.y + pg3 * v3.y;
                ov.z += pg0 * v0.z + pg1 * v1.z + pg2 * v2.z + pg3 * v3.z;
                ov.w += pg0 * v0.w + pg1 * v1.w + pg2 * v2.w + pg3 * v3.w;
            }
            union { _Float16 h[4]; ushort4 u; } cc;
            cc.h[0] = (_Float16)(ov.x * linv); cc.h[1] = (_Float16)(ov.y * linv);
            cc.h[2] = (_Float16)(ov.z * linv); cc.h[3] = (_Float16)(ov.w * linv);
            *(ushort4*)(arow + d) = cc.u;
        }
    }
}

// ---------------------------------------------------------------------------
// Global-ROW attention partials: grid (12 col-chunks, 64 bhi), 256 thr.
// ---------------------------------------------------------------------------
__global__ __launch_bounds__(256) void grows_part(
    const _Float16* __restrict__ qkvh, const _Float16* __restrict__ rkh,
    const float* __restrict__ drk, const float* __restrict__ cb,
    float* __restrict__ g_O, float* __restrict__ g_l)
{
    __shared__ float qc_s[64];
    __shared__ float p_s[128];
    __shared__ float obuf[4][64];
    __shared__ float lred[2];
    const int chunk = blockIdx.x;        // 0..11
    const int bhi = blockIdx.y;          // 0..63
    const int i = bhi & 3, h = (bhi >> 2) & 7, b = bhi >> 5;
    const int t = threadIdx.x;
    const int c0 = chunk * 128;
    if (t < 64)
        qc_s[t] = (float)qkvh[(size_t)(b * NSEQ + i) * HD3 + h * 64 + t]
                  + cb[h * 64 + t];
    __syncthreads();
    if (t < 128) {
        int j = c0 + t;
        const _Float16* krow = qkvh + (size_t)(b * NSEQ + j) * HD3 + 512 + h * 64;
        int jj = j - i + (NSEQ - 1);
        const _Float16* rrow = rkh + (size_t)jj * RKLD + h * 64;
        float s0 = 0, s1 = 0, s2 = 0, s3 = 0;
#pragma unroll
        for (int d4 = 0; d4 < 16; ++d4) {
            f16x4 kv = *(const f16x4*)(krow + d4 * 4);
            f16x4 rv = *(const f16x4*)(rrow + d4 * 4);
            float4 qv = *(const float4*)(&qc_s[d4 * 4]);
            s0 = fmaf(qv.x, (float)kv[0] + (float)rv[0], s0);
            s1 = fmaf(qv.y, (float)kv[1] + (float)rv[1], s1);
            s2 = fmaf(qv.z, (float)kv[2] + (float)rv[2], s2);
            s3 = fmaf(qv.w, (float)kv[3] + (float)rv[3], s3);
        }
        float p = __expf((s0 + s1) + (s2 + s3) + drk[h * RLEN + jj]);
        p_s[t] = p;
        float ls = p;
#pragma unroll
        for (int off = 32; off > 0; off >>= 1)
            ls += __shfl_down(ls, off, 64);
        if ((t & 63) == 0) lred[t >> 6] = ls;
    }
    __syncthreads();
    {
        const int d = t & 63, g = t >> 6;
        float a0 = 0, a1 = 0;
        const unsigned short* vbase = (const unsigned short*)qkvh
            + (size_t)(b * NSEQ + c0 + g * 32) * HD3 + 1024 + h * 64 + d;
#pragma unroll
        for (int j2 = 0; j2 < 32; j2 += 2) {
            a0 = fmaf(p_s[g * 32 + j2],     bf2f(vbase[(size_t)j2 * HD3]),       a0);
            a1 = fmaf(p_s[g * 32 + j2 + 1], bf2f(vbase[(size_t)(j2 + 1) * HD3]), a1);
        }
        obuf[g][d] = a0 + a1;
    }
    __syncthreads();
    if (t < 64) {
        float o = (obuf[0][t] + obuf[1][t]) + (obuf[2][t] + obuf[3][t]);
        g_O[((size_t)chunk * 64 + bhi) * 64 + t] = o;
        if (t == 0) g_l[chunk * 64 + bhi] = lred[0] + lred[1];
    }
}

// ---------------------------------------------------------------------------
// Overwrite the 64 global rows (i<4 per b,h) of aoh from grows_part partials.
// grid 16 (=bh), 256 thr: i = t>>6, d = t&63.
// ---------------------------------------------------------------------------
__global__ __launch_bounds__(256) void gfix(
    const float* __restrict__ g_O, const float* __restrict__ g_l,
    _Float16* __restrict__ aoh)
{
    const int bh = blockIdx.x, b = bh >> 3, h = bh & 7;
    const int i = threadIdx.x >> 6, d = threadIdx.x & 63;
    const int bhi = bh * 4 + i;
    float o = 0.f, l = 0.f;
#pragma unroll
    for (int c = 0; c < 12; ++c) {
        o += g_O[((size_t)c * 64 + bhi) * 64 + d];
        l += g_l[c * 64 + bhi];
    }
    aoh[((size_t)(b * NSEQ + i)) * 512 + h * 64 + d] = (_Float16)(o / l);
}

// ---------------------------------------------------------------------------
extern "C" void kernel_launch(void* const* d_in, const int* in_sizes, int n_in,
                              void* d_out, int out_size, void* d_ws, size_t ws_size,
                              hipStream_t stream)
{
    const float* x    = (const float*)d_in[0];
    const float* Wq   = (const float*)d_in[1];
    const float* Wk   = (const float*)d_in[2];
    const float* Wv   = (const float*)d_in[3];
    const float* Wrel = (const float*)d_in[4];
    const float* cb   = (const float*)d_in[5];
    const float* rb   = (const float*)d_in[6];
    const float* Wo   = (const float*)d_in[7];
    const float* bo   = (const float*)d_in[8];
    const float* pe   = (const float*)d_in[9];
    float* out = (float*)d_out;

    float* ws = (float*)d_ws;
    _Float16* qkvh = (_Float16*)ws;                      // [3072][1536] Q,K f16 | V bf16
    _Float16* rkh  = (_Float16*)(ws + 2359296);          // [3072][512] f16 (row 3071 scratch)
    float* drk   = ws + 3145728;                         // [8][3071] f32
    _Float16* aoh = (_Float16*)(ws + 3170304);           // [3072][512] f16
    _Float16* woh = (_Float16*)(ws + 3956736);           // WoT [1536][512] f16
    float* R = ws + 4349952;                             // aliased region
    _Float16* relbT = (_Float16*)R;                          // [16][12][512][128] f16
    _Float16* xh  = (_Float16*)R;                            // dead before relbT written
    _Float16* wqh = (_Float16*)(R + 2359296);                // WqkvT [1536][1536] f16
    float* g_O = R + 6291456;                            // [12][64][64] f32 (after relbT)
    float* g_l = R + 6340608;                            // [12][64] f32
    _Float16* peh   = (_Float16*)(ws + 15483648);        // [3072][192] f16 (row 3071 scratch)
    _Float16* wrelT = (_Float16*)(ws + 15778560);        // WrelT [512][192] f16

    dim3 blk(256);
    split2_f16<<<5184, blk, 0, stream>>>(x, xh, pe, peh);
    wsplit_all<<<dim3(8, 24, 5), blk, 0, stream>>>(Wq, Wk, Wv, Wo, Wrel,
                                                   wqh, woh, wrelT);
    gemm_f16k<<<dim3(24, 48), blk, 0, stream>>>(xh, wqh, nullptr, qkvh,
                                                3072, 1536, 1536, 1);
    gemm_f16k<<<dim3(8, 48), blk, 0, stream>>>(peh, wrelT, nullptr, rkh,
                                               3072, 512, 192, 2);
    drk_kernel<<<96, blk, 0, stream>>>(rkh, cb, rb, drk);
    relb_mfma<<<dim3(4, 12, 16), blk, 0, stream>>>(qkvh, rkh, rb, relbT);
    attn_flash<<<dim3(12, 16, 2), blk, 0, stream>>>(qkvh, relbT, rkh, drk, cb, aoh);
    grows_part<<<dim3(12, 64), blk, 0, stream>>>(qkvh, rkh, drk, cb, g_O, g_l);
    gfix<<<16, blk, 0, stream>>>(g_O, g_l, aoh);
    gemm_f16k<<<dim3(24, 48), blk, 0, stream>>>(aoh, woh, bo, out,
                                                3072, 1536, 512, 0);
}

// Round 9
// 220.268 us; speedup vs baseline: 1.0493x; 1.0174x over previous
//
#include <hip/hip_runtime.h>
#include <math.h>

#define NSEQ 1536
#define HD3  1536      // fused qkv row stride
#define RKLD 512       // rel_k row stride
#define RLEN 3071
#define NB   12

typedef __attribute__((ext_vector_type(8))) short bf16x8;
typedef __attribute__((ext_vector_type(4))) float f32x4;
typedef _Float16 f16x8 __attribute__((ext_vector_type(8)));
typedef _Float16 f16x4 __attribute__((ext_vector_type(4)));

__device__ __forceinline__ unsigned short f2bf(float f) {
    union { float f; unsigned u; } v; v.f = f;
    unsigned r = v.u + 0x7fffu + ((v.u >> 16) & 1u);
    return (unsigned short)(r >> 16);
}
__device__ __forceinline__ float bf2f(unsigned short s) {
    union { unsigned u; float f; } v; v.u = ((unsigned)s) << 16;
    return v.f;
}
__device__ __forceinline__ unsigned short f2h(float f) {
    union { _Float16 h; unsigned short u; } c; c.h = (_Float16)f; return c.u;
}
__device__ __forceinline__ void cp16(const void* g, void* l) {
    __builtin_amdgcn_global_load_lds(
        (const __attribute__((address_space(1))) void*)g,
        (__attribute__((address_space(3))) void*)l, 16, 0, 0);
}

// LDS swizzles: keep 8-elem chunks contiguous; XOR chunk id with row bits to
// break power-of-2 stride bank conflicts.
#define KSWZ(row, d) ((row) * 64 + (((((d) >> 3) ^ ((row) & 7))) << 3) + ((d) & 7))
#define PSWZ(r, j)   ((r) * 128 + (((((j) >> 3) ^ ((r) & 15))) << 3) + ((j) & 7))
#define VSTR 136     // Vt row stride in elems (272B: 16B-aligned, non-pow2)

// ---------------------------------------------------------------------------
// Weight transpose body: W[K][N] f32 -> T[n_off+N][ldt] f16
// ---------------------------------------------------------------------------
__device__ __forceinline__ void wsplit_body16(
    const float* __restrict__ W, _Float16* __restrict__ T,
    int K, int N, int n_off, int ldt, float scale, int bx, int by)
{
    __shared__ float tile[64][65];
    const int k0 = by * 64, n0 = bx * 64;
    const int t = threadIdx.x;
    const int rr = t >> 4, c4 = (t & 15) * 4;
#pragma unroll
    for (int p = 0; p < 4; ++p) {
        int r = p * 16 + rr;
        float4 v = *(const float4*)(W + (size_t)(k0 + r) * N + n0 + c4);
        tile[r][c4 + 0] = v.x; tile[r][c4 + 1] = v.y;
        tile[r][c4 + 2] = v.z; tile[r][c4 + 3] = v.w;
    }
    __syncthreads();
#pragma unroll
    for (int p = 0; p < 4; ++p) {
        int n = p * 16 + rr;
        union { _Float16 h[4]; ushort4 u; } cc;
        cc.h[0] = (_Float16)(tile[c4 + 0][n] * scale);
        cc.h[1] = (_Float16)(tile[c4 + 1][n] * scale);
        cc.h[2] = (_Float16)(tile[c4 + 2][n] * scale);
        cc.h[3] = (_Float16)(tile[c4 + 3][n] * scale);
        size_t o = (size_t)(n_off + n0 + n) * ldt + k0 + c4;
        *(ushort4*)(T + o) = cc.u;
    }
}

// ---------------------------------------------------------------------------
// ONE prep launch (R9): blocks 0..4607 convert x->f16; 4608..5183 convert
// pos_embed; 5184..6143 transpose all five weights. Independent work merged
// to cut launch-gap overhead (10 -> 8 kernels total).
// ---------------------------------------------------------------------------
__global__ __launch_bounds__(256) void prep_all(
    const float* __restrict__ X, _Float16* __restrict__ HX,
    const float* __restrict__ P, _Float16* __restrict__ HP,
    const float* __restrict__ Wq, const float* __restrict__ Wk,
    const float* __restrict__ Wv, const float* __restrict__ Wo,
    const float* __restrict__ Wrel,
    _Float16* __restrict__ Tqkv, _Float16* __restrict__ To,
    _Float16* __restrict__ Trel)
{
    const int bid = blockIdx.x;
    if (bid < 5184) {
        const float* src; _Float16* dst; int i;
        if (bid < 4608) {                    // 4608*256 == 1179648 exactly
            i = bid * 256 + threadIdx.x;
            src = X; dst = HX;
        } else {
            i = (bid - 4608) * 256 + threadIdx.x;
            if (i >= 147408) return;         // 3071*192/4
            src = P; dst = HP;
        }
        float4 v = ((const float4*)src)[i];
        union { _Float16 h[4]; ushort4 u; } c;
        c.h[0] = (_Float16)v.x; c.h[1] = (_Float16)v.y;
        c.h[2] = (_Float16)v.z; c.h[3] = (_Float16)v.w;
        ((ushort4*)dst)[i] = c.u;
        return;
    }
    const int u = bid - 5184;                // 0..959
    const int z = u / 192, r = u % 192;
    if (z < 3) {
        const float* W = (z == 0) ? Wq : (z == 1) ? Wk : Wv;
        wsplit_body16(W, Tqkv, 1536, 512, z * 512, 1536,
                      (z == 0) ? 0.125f : 1.f, r % 8, r / 8);
    } else if (z == 3) {
        wsplit_body16(Wo, To, 512, 1536, 0, 512, 1.f, r / 8, r % 8);
    } else {
        if (r / 8 >= 3) return;              // uniform per block, pre-barrier
        wsplit_body16(Wrel, Trel, 192, 512, 0, 192, 1.f, r % 8, r / 8);
    }
}

// ---------------------------------------------------------------------------
// Single-term f16 MFMA GEMM, 64x64 tile, BK=64: C = A·B^T (+bias).
// 2-buffer single-barrier; 32KB LDS; KSWZ; XCD swizzle.
// omode 0: C f32 + bias. omode 1: QKV split store — cols<1024 f16 (Q,K),
// cols>=1024 bf16 (V: must pair with bf16 P in the PV MFMA). omode 2: f16.
// ---------------------------------------------------------------------------
__global__ __launch_bounds__(256) void gemm_f16k(
    const _Float16* __restrict__ A,   // [M][K] f16
    const _Float16* __restrict__ B,   // [N][K] f16 (pre-transposed weight)
    const float* __restrict__ bias, void* __restrict__ C,
    int M, int N, int K, int omode)
{
    __shared__ _Float16 sA[2][4096];    // [buf][64*64]
    __shared__ _Float16 sB[2][4096];
    const int t = threadIdx.x;
    const int wave = t >> 6, lane = t & 63;
    // XCD-aware bijective swizzle (nwg % 8 == 0 for all launches here)
    const int nwg = gridDim.x * gridDim.y;
    const int lin = blockIdx.y * gridDim.x + blockIdx.x;
    const int swz = (lin & 7) * (nwg >> 3) + (lin >> 3);
    const int bx = swz % gridDim.x, by = swz / gridDim.x;
    const int m0 = by * 64, n0 = bx * 64;
    const int wm = (wave >> 1) * 32, wn = (wave & 1) * 32;
    const int fr = lane & 15, quad = lane >> 4;

    f32x4 acc[2][2];
#pragma unroll
    for (int i = 0; i < 2; ++i)
#pragma unroll
        for (int j = 0; j < 2; ++j)
#pragma unroll
            for (int c = 0; c < 4; ++c) acc[i][j][c] = 0.f;

    const int nsteps = K >> 6;

#define STAGE(k0, buf)                                                        \
    {                                                                         \
        _Pragma("unroll")                                                     \
        for (int it = 0; it < 2; ++it) {                                      \
            int cidx = it * 256 + t;                                          \
            int row = cidx >> 3, slot = cidx & 7;                             \
            int gch = slot ^ (row & 7);                                       \
            size_t goA = (size_t)(m0 + row) * K + (k0) + gch * 8;             \
            size_t goB = (size_t)(n0 + row) * K + (k0) + gch * 8;             \
            cp16(A + goA, &sA[buf][it * 2048 + wave * 512]);                  \
            cp16(B + goB, &sB[buf][it * 2048 + wave * 512]);                  \
        }                                                                     \
    }

    STAGE(0, 0);
    for (int s = 0; s < nsteps; ++s) {
        const int buf = s & 1;
        __syncthreads();
        if (s + 1 < nsteps) STAGE((s + 1) * 64, buf ^ 1);

        f16x8 fa[2][2], fb[2][2];
#pragma unroll
        for (int ti = 0; ti < 2; ++ti)
#pragma unroll
            for (int kc = 0; kc < 2; ++kc) {
                fa[ti][kc] = *(const f16x8*)&sA[buf][KSWZ(wm + ti * 16 + fr,
                                                          kc * 32 + quad * 8)];
                fb[ti][kc] = *(const f16x8*)&sB[buf][KSWZ(wn + ti * 16 + fr,
                                                          kc * 32 + quad * 8)];
            }
#pragma unroll
        for (int ti = 0; ti < 2; ++ti)
#pragma unroll
            for (int tj = 0; tj < 2; ++tj)
#pragma unroll
                for (int kc = 0; kc < 2; ++kc)
                    acc[ti][tj] = __builtin_amdgcn_mfma_f32_16x16x32_f16(
                        fa[ti][kc], fb[tj][kc], acc[ti][tj], 0, 0, 0);
    }
#undef STAGE

    if (omode == 0) {
        float* Cf = (float*)C;
#pragma unroll
        for (int ti = 0; ti < 2; ++ti) {
            int rowb = m0 + wm + ti * 16 + quad * 4;
#pragma unroll
            for (int tj = 0; tj < 2; ++tj) {
                int col = n0 + wn + tj * 16 + fr;
                float bb = bias ? bias[col] : 0.f;
#pragma unroll
                for (int j2 = 0; j2 < 4; ++j2)
                    Cf[(size_t)(rowb + j2) * N + col] = acc[ti][tj][j2] + bb;
            }
        }
    } else {
        unsigned short* Cu = (unsigned short*)C;
        const bool vb = (omode == 1) && (n0 >= 1024);   // V region -> bf16
#pragma unroll
        for (int ti = 0; ti < 2; ++ti) {
            int rowb = m0 + wm + ti * 16 + quad * 4;
#pragma unroll
            for (int tj = 0; tj < 2; ++tj) {
                int col = n0 + wn + tj * 16 + fr;
#pragma unroll
                for (int j2 = 0; j2 < 4; ++j2) {
                    float v = acc[ti][tj][j2];
                    Cu[(size_t)(rowb + j2) * N + col] = vb ? f2bf(v) : f2h(v);
                }
            }
        }
    }
}

// ---------------------------------------------------------------------------
// Banded rel logits via f16 MFMA (z<16) + drk reduction (z>=16, R9-folded:
// drk[h][jj] = sum_d (rpb-rcb)[h,d] * rk[jj,h*64+d]; 96 blocks, no LDS/sync).
// rk band staged DIRECT via global_load_lds (pre-swizzled source).
// Output SHIFTED+TRANSPOSED f16: relbT[bh][bi][jl][r], jl = ccg-127+r.
// ---------------------------------------------------------------------------
__global__ __launch_bounds__(256) void relb_mfma(
    const _Float16* __restrict__ qkvh, const _Float16* __restrict__ rkh,
    const float* __restrict__ rb, const float* __restrict__ cb,
    float* __restrict__ drk, _Float16* __restrict__ relbT)
{
    __shared__ _Float16 sR[8192];   // 128 band rows x 64 d
    const int ct = blockIdx.x, bi = blockIdx.y, bz = blockIdx.z;
    const int t = threadIdx.x;
    if (bz >= 16) {                 // ---- folded drk blocks (2*48 = 96) ----
        int blk = (bz - 16) * 48 + bi * 4 + ct;     // 0..95
        int idx = blk * 256 + t;
        if (idx >= 8 * RLEN) return;
        int jj = idx >> 3, h = idx & 7;
        const _Float16* rrow = rkh + (size_t)jj * RKLD + h * 64;
        float s0 = 0, s1 = 0, s2 = 0, s3 = 0;
#pragma unroll
        for (int d4 = 0; d4 < 16; ++d4) {
            f16x4 rv = *(const f16x4*)(rrow + d4 * 4);
            float dx = rb[h * 64 + d4 * 4 + 0] - cb[h * 64 + d4 * 4 + 0];
            float dy = rb[h * 64 + d4 * 4 + 1] - cb[h * 64 + d4 * 4 + 1];
            float dz = rb[h * 64 + d4 * 4 + 2] - cb[h * 64 + d4 * 4 + 2];
            float dw = rb[h * 64 + d4 * 4 + 3] - cb[h * 64 + d4 * 4 + 3];
            s0 = fmaf(dx, (float)rv[0], s0); s1 = fmaf(dy, (float)rv[1], s1);
            s2 = fmaf(dz, (float)rv[2], s2); s3 = fmaf(dw, (float)rv[3], s3);
        }
        drk[h * RLEN + jj] = (s0 + s1) + (s2 + s3);
        return;
    }
    const int bh = bz;
    const int b = bh >> 3, h = bh & 7;
    const int i0 = bi * 128;
    const int c0 = (bi == 0) ? 0 : (bi - 1) * 128;
    const int jjbase = c0 - i0 - 127 + (NSEQ - 1) + ct * 128;  // in [1280,1920)
    const int wave = t >> 6, lane = t & 63;
    const int fr = lane & 15, quad = lane >> 4;

    // ---- stage rk band: direct global->LDS, pre-swizzled source ----
    {
        const _Float16* Rg = rkh + (size_t)jjbase * RKLD + h * 64;
#pragma unroll
        for (int it = 0; it < 4; ++it) {
            int cidx = it * 256 + t;           // 0..1023 chunk id
            int row = cidx >> 3, slot = cidx & 7;
            int gch = slot ^ (row & 7);
            cp16(Rg + (size_t)row * RKLD + gch * 8,
                 &sR[it * 2048 + wave * 512]);
        }
    }
    // ---- Q + rel-pos-bias fragments (f16 source) ----
    f16x8 qf[2][2];
    {
        const _Float16* Qg = qkvh + ((size_t)(b * NSEQ + i0)) * HD3 + h * 64;
#pragma unroll
        for (int ti = 0; ti < 2; ++ti)
#pragma unroll
            for (int kc = 0; kc < 2; ++kc) {
                int m = wave * 32 + ti * 16 + fr;
                int k8 = kc * 32 + quad * 8;
                f16x8 qv = *(const f16x8*)(Qg + (size_t)m * HD3 + k8);
                const float* cp = rb + h * 64 + k8;
                _Float16 hx[8];
#pragma unroll
                for (int u = 0; u < 8; ++u)
                    hx[u] = (_Float16)((float)qv[u] + cp[u]);
                qf[ti][kc] = *(f16x8*)hx;
            }
    }
    __syncthreads();

    // ---- S = (Q+rpb) · rk^T ----
    f32x4 sacc[2][8];
#pragma unroll
    for (int i = 0; i < 2; ++i)
#pragma unroll
        for (int j = 0; j < 8; ++j)
#pragma unroll
            for (int c = 0; c < 4; ++c) sacc[i][j][c] = 0.f;

#pragma unroll
    for (int kc = 0; kc < 2; ++kc) {
        f16x8 bv[8];
#pragma unroll
        for (int tj = 0; tj < 8; ++tj)
            bv[tj] = *(const f16x8*)&sR[KSWZ(tj * 16 + fr, kc * 32 + quad * 8)];
#pragma unroll
        for (int ti = 0; ti < 2; ++ti)
#pragma unroll
            for (int tj = 0; tj < 8; ++tj)
                sacc[ti][tj] = __builtin_amdgcn_mfma_f32_16x16x32_f16(
                    qf[ti][kc], bv[tj], sacc[ti][tj], 0, 0, 0);
    }

    // ---- shifted scatter-store to relbT ----
    size_t bb_ = ((size_t)bh * NB + bi) * 512;
#pragma unroll
    for (int ti = 0; ti < 2; ++ti) {
        int mr = wave * 32 + ti * 16 + quad * 4;
#pragma unroll
        for (int tj = 0; tj < 8; ++tj) {
            int ccg = ct * 128 + tj * 16 + fr;
#pragma unroll
            for (int reg = 0; reg < 4; ++reg) {
                int r = mr + reg;
                int jl = ccg - 127 + r;            // < 512 always
                if (jl >= 0)
                    relbT[(bb_ + jl) * 128 + r] = (_Float16)sacc[ti][tj][reg];
            }
        }
    }
}

// ---------------------------------------------------------------------------
// FLASH attention, 64-ROW Q blocks: grid (bi 12, bh 16, qz 2) = 384 blocks.
// Each block loops its 2-3 local K/V tiles, accumulating O/l in registers
// (unnormalized softmax — no rescale). LDS ~35KB: K and P share sKP.
// Global rows (i<4) overwritten later by gfix. bi>=2 folds in 4 gcols.
// ---------------------------------------------------------------------------
__global__ __launch_bounds__(256) void attn_flash(
    const _Float16* __restrict__ qkvh, const _Float16* __restrict__ relbT,
    const _Float16* __restrict__ rkh, const float* __restrict__ drk,
    const float* __restrict__ cb, _Float16* __restrict__ aoh)
{
    __shared__ unsigned short sKP[8192];    // K f16 (128x64) -> P bf16 (64x128)
    __shared__ unsigned short sVt[64 * VSTR];  // V^T bf16 [d][VSTR]
    __shared__ float p_g[64 * 4];           // gcols p per (row, j)
    __shared__ __align__(16) float vg[4 * 64];  // global V rows 0..3
    __shared__ float lg[64];                // gcols l per row
    __shared__ float lrow[64];              // local l per row (post-reduce)
    const int bi = blockIdx.x, bh = blockIdx.y, qz = blockIdx.z;
    const int b = bh >> 3, h = bh & 7;
    const int i0 = bi * 128 + qz * 64;      // this block's 64 Q rows
    const int c0 = (bi == 0) ? 0 : (bi - 1) * 128;
    const int c1 = (bi == NB - 1) ? NSEQ : (bi + 2) * 128;
    const int nt = (c1 - c0) >> 7;          // 2 or 3 tiles
    const int t = threadIdx.x;
    const int wave = t >> 6, lane = t & 63;
    const int fr = lane & 15, quad = lane >> 4;
    const bool do_g = (bi >= 2);
    const unsigned short* Vall = (const unsigned short*)qkvh;

    // ---- fused global-column (cols 0..3) contribution, once per block ----
    if (do_g) {
        if (t < 64) {
            const int r = t;
            const int i = i0 + r;
            const int jjb = NSEQ - 1 - i;       // jj for j=0; j adds +j
            const _Float16* qrow = qkvh + (size_t)(b * NSEQ + i) * HD3 + h * 64;
            const _Float16* krow = qkvh + (size_t)(b * NSEQ) * HD3 + 512 + h * 64;
            const _Float16* rrow = rkh + (size_t)jjb * RKLD + h * 64;
            float s[4] = {0.f, 0.f, 0.f, 0.f};
#pragma unroll
            for (int d4 = 0; d4 < 16; ++d4) {
                f16x4 qv = *(const f16x4*)(qrow + d4 * 4);
                float4 cv = *(const float4*)(cb + h * 64 + d4 * 4);
                float q0 = (float)qv[0] + cv.x, q1 = (float)qv[1] + cv.y;
                float q2 = (float)qv[2] + cv.z, q3 = (float)qv[3] + cv.w;
#pragma unroll
                for (int j = 0; j < 4; ++j) {
                    f16x4 kv = *(const f16x4*)(krow + (size_t)j * HD3 + d4 * 4);
                    f16x4 rv = *(const f16x4*)(rrow + (size_t)j * RKLD + d4 * 4);
                    s[j] = fmaf(q0, (float)kv[0] + (float)rv[0], s[j]);
                    s[j] = fmaf(q1, (float)kv[1] + (float)rv[1], s[j]);
                    s[j] = fmaf(q2, (float)kv[2] + (float)rv[2], s[j]);
                    s[j] = fmaf(q3, (float)kv[3] + (float)rv[3], s[j]);
                }
            }
            float l = 0.f;
#pragma unroll
            for (int j = 0; j < 4; ++j) {
                float p = __expf(s[j] + drk[h * RLEN + jjb + j]);
                p_g[r * 4 + j] = p;
                l += p;
            }
            lg[r] = l;
        } else if (t >= 128) {
            const unsigned short* Vg0 = Vall + (size_t)(b * NSEQ) * HD3
                                        + 1024 + h * 64;
            int u = (t - 128) * 2;
#pragma unroll
            for (int w = 0; w < 2; ++w) {
                int idx = u + w;               // j*64 + d
                vg[idx] = bf2f(Vg0[(size_t)(idx >> 6) * HD3 + (idx & 63)]);
            }
        }
    }
    // ---- Q fragments in registers (f16 q + content bias), once ----
    f16x8 qf[2];
    {
        const _Float16* Qg = qkvh + ((size_t)(b * NSEQ + i0)) * HD3 + h * 64;
        const int m = wave * 16 + fr;
#pragma unroll
        for (int kc = 0; kc < 2; ++kc) {
            int k8 = kc * 32 + quad * 8;
            f16x8 qv = *(const f16x8*)(Qg + (size_t)m * HD3 + k8);
            const float* cp = cb + h * 64 + k8;
            _Float16 hx[8];
#pragma unroll
            for (int u = 0; u < 8; ++u)
                hx[u] = (_Float16)((float)qv[u] + cp[u]);
            qf[kc] = *(f16x8*)hx;
        }
    }

    // ---- persistent accumulators across tiles ----
    f32x4 oacc[4];
#pragma unroll
    for (int i = 0; i < 4; ++i)
#pragma unroll
        for (int c = 0; c < 4; ++c) oacc[i][c] = 0.f;
    float lsum[4] = {0.f, 0.f, 0.f, 0.f};

    for (int ct = 0; ct < nt; ++ct) {
        const int ctile = c0 + ct * 128;
        // ---- stage K: direct global->LDS, pre-swizzled source (f16 bits) ----
        {
            const _Float16* Kg = qkvh + ((size_t)(b * NSEQ + ctile)) * HD3
                                 + 512 + h * 64;
#pragma unroll
            for (int it = 0; it < 4; ++it) {
                int cidx = it * 256 + t;           // 0..1023
                int row = cidx >> 3, slot = cidx & 7;
                int gch = slot ^ (row & 7);
                cp16(Kg + (size_t)row * HD3 + gch * 8,
                     (unsigned short*)&sKP[it * 2048 + wave * 512]);
            }
        }
        // ---- stage V transposed (bf16 bits, pure moves, [d][VSTR]) ----
        {
            const unsigned short* Vg = Vall + ((size_t)(b * NSEQ + ctile)) * HD3
                                       + 1024 + h * 64;
#pragma unroll
            for (int it = 0; it < 2; ++it) {
                int lin = it * 256 + t;            // 0..511
                int r4 = (lin >> 4) * 4, d4 = (lin & 15) * 4;
                ushort4 v0 = *(const ushort4*)(Vg + (size_t)(r4 + 0) * HD3 + d4);
                ushort4 v1 = *(const ushort4*)(Vg + (size_t)(r4 + 1) * HD3 + d4);
                ushort4 v2 = *(const ushort4*)(Vg + (size_t)(r4 + 2) * HD3 + d4);
                ushort4 v3 = *(const ushort4*)(Vg + (size_t)(r4 + 3) * HD3 + d4);
                const unsigned short* p0 = (const unsigned short*)&v0;
                const unsigned short* p1 = (const unsigned short*)&v1;
                const unsigned short* p2 = (const unsigned short*)&v2;
                const unsigned short* p3 = (const unsigned short*)&v3;
#pragma unroll
                for (int dd = 0; dd < 4; ++dd) {
                    ushort4 hh;
                    hh.x = p0[dd]; hh.y = p1[dd]; hh.z = p2[dd]; hh.w = p3[dd];
                    *(ushort4*)&sVt[(d4 + dd) * VSTR + r4] = hh;
                }
            }
        }
        __syncthreads();

        // ---- S = Q K^T (f16 MFMA, f32 accum), 64 rows x 128 cols ----
        f32x4 sacc[8];
#pragma unroll
        for (int j = 0; j < 8; ++j)
#pragma unroll
            for (int c = 0; c < 4; ++c) sacc[j][c] = 0.f;

#pragma unroll
        for (int kc = 0; kc < 2; ++kc) {
            f16x8 bv[8];
#pragma unroll
            for (int tj = 0; tj < 8; ++tj)
                bv[tj] = *(const f16x8*)&sKP[KSWZ(tj * 16 + fr,
                                                  kc * 32 + quad * 8)];
#pragma unroll
            for (int tj = 0; tj < 8; ++tj)
                sacc[tj] = __builtin_amdgcn_mfma_f32_16x16x32_f16(
                    qf[kc], bv[tj], sacc[tj], 0, 0, 0);
        }
        __syncthreads();   // all waves done reading K before P overwrites it

        // ---- rel + exp -> P (bf16, PSWZ, 64x128); row-sums accumulate ----
        const _Float16* relbase = relbT
            + (((size_t)bh * NB + bi) * 512 + ct * 128) * 128;
        {
            int mr = wave * 16 + quad * 4;              // local row in [0,64)
            int mr128 = qz * 64 + mr;                   // row in relbT's 128-space
#pragma unroll
            for (int tj = 0; tj < 8; ++tj) {
                int j = tj * 16 + fr;
                f16x4 rl = *(const f16x4*)&relbase[(size_t)j * 128 + mr128];
#pragma unroll
                for (int reg = 0; reg < 4; ++reg) {
                    int r = mr + reg;
                    float p = __expf(sacc[tj][reg] + (float)rl[reg]);
                    unsigned short pb = f2bf(p);
                    lsum[reg] += bf2f(pb);     // l consistent with bf16 P
                    sKP[PSWZ(r, j)] = pb;
                }
            }
        }
        // (no barrier: each wave consumes only its own 16 P rows below)

        // ---- O^T += Vt x P^T (bf16 MFMA) ----
#pragma unroll
        for (int kc = 0; kc < 4; ++kc) {
            int r = wave * 16 + fr;
            bf16x8 pbv = *(const bf16x8*)&sKP[PSWZ(r, kc * 32 + quad * 8)];
#pragma unroll
            for (int dt = 0; dt < 4; ++dt) {
                bf16x8 av = *(const bf16x8*)&sVt[(dt * 16 + fr) * VSTR
                                                 + kc * 32 + quad * 8];
                oacc[dt] = __builtin_amdgcn_mfma_f32_16x16x32_bf16(
                    av, pbv, oacc[dt], 0, 0, 0);
            }
        }
        __syncthreads();   // before next tile's staging overwrites sKP/sVt
    }

    // ---- reduce l across fr lanes; publish per-row l in LDS ----
#pragma unroll
    for (int m2 = 1; m2 < 16; m2 <<= 1)
#pragma unroll
        for (int reg = 0; reg < 4; ++reg)
            lsum[reg] += __shfl_xor(lsum[reg], m2, 64);
    if (fr == 0) {
        int mr = wave * 16 + quad * 4;
#pragma unroll
        for (int reg = 0; reg < 4; ++reg)
            lrow[mr + reg] = lsum[reg];
    }
    __syncthreads();

    // ---- normalize + (gcols) + write aoh f16 ----
    {
        int r = wave * 16 + fr;
        float l = lrow[r] + (do_g ? lg[r] : 0.f);
        float linv = 1.f / l;
        float pg0 = 0.f, pg1 = 0.f, pg2 = 0.f, pg3 = 0.f;
        if (do_g) {
            pg0 = p_g[r * 4 + 0]; pg1 = p_g[r * 4 + 1];
            pg2 = p_g[r * 4 + 2]; pg3 = p_g[r * 4 + 3];
        }
        _Float16* arow = aoh + ((size_t)(b * NSEQ + i0 + r)) * 512 + h * 64;
#pragma unroll
        for (int dt = 0; dt < 4; ++dt) {
            int d = dt * 16 + quad * 4;
            float4 ov = make_float4(oacc[dt][0], oacc[dt][1],
                                    oacc[dt][2], oacc[dt][3]);
            if (do_g) {
                float4 v0 = *(const float4*)&vg[0 * 64 + d];
                float4 v1 = *(const float4*)&vg[1 * 64 + d];
                float4 v2 = *(const float4*)&vg[2 * 64 + d];
                float4 v3 = *(const float4*)&vg[3 * 64 + d];
                ov.x += pg0 * v0.x + pg1 * v1.x + pg2 * v2.x + pg3 * v3.x;
                ov.y += pg0 * v0.y + pg1 * v1.y + pg2 * v2.y + pg3 * v3.y;
                ov.z += pg0 * v0.z + pg1 * v1.z + pg2 * v2.z + pg3 * v3.z;
                ov.w += pg0 * v0.w + pg1 * v1.w + pg2 * v2.w + pg3 * v3.w;
            }
            union { _Float16 h[4]; ushort4 u; } cc;
            cc.h[0] = (_Float16)(ov.x * linv); cc.h[1] = (_Float16)(ov.y * linv);
            cc.h[2] = (_Float16)(ov.z * linv); cc.h[3] = (_Float16)(ov.w * linv);
            *(ushort4*)(arow + d) = cc.u;
        }
    }
}

// ---------------------------------------------------------------------------
// Global-ROW attention partials: grid (12 col-chunks, 64 bhi), 256 thr.
// ---------------------------------------------------------------------------
__global__ __launch_bounds__(256) void grows_part(
    const _Float16* __restrict__ qkvh, const _Float16* __restrict__ rkh,
    const float* __restrict__ drk, const float* __restrict__ cb,
    float* __restrict__ g_O, float* __restrict__ g_l)
{
    __shared__ float qc_s[64];
    __shared__ float p_s[128];
    __shared__ float obuf[4][64];
    __shared__ float lred[2];
    const int chunk = blockIdx.x;        // 0..11
    const int bhi = blockIdx.y;          // 0..63
    const int i = bhi & 3, h = (bhi >> 2) & 7, b = bhi >> 5;
    const int t = threadIdx.x;
    const int c0 = chunk * 128;
    if (t < 64)
        qc_s[t] = (float)qkvh[(size_t)(b * NSEQ + i) * HD3 + h * 64 + t]
                  + cb[h * 64 + t];
    __syncthreads();
    if (t < 128) {
        int j = c0 + t;
        const _Float16* krow = qkvh + (size_t)(b * NSEQ + j) * HD3 + 512 + h * 64;
        int jj = j - i + (NSEQ - 1);
        const _Float16* rrow = rkh + (size_t)jj * RKLD + h * 64;
        float s0 = 0, s1 = 0, s2 = 0, s3 = 0;
#pragma unroll
        for (int d4 = 0; d4 < 16; ++d4) {
            f16x4 kv = *(const f16x4*)(krow + d4 * 4);
            f16x4 rv = *(const f16x4*)(rrow + d4 * 4);
            float4 qv = *(const float4*)(&qc_s[d4 * 4]);
            s0 = fmaf(qv.x, (float)kv[0] + (float)rv[0], s0);
            s1 = fmaf(qv.y, (float)kv[1] + (float)rv[1], s1);
            s2 = fmaf(qv.z, (float)kv[2] + (float)rv[2], s2);
            s3 = fmaf(qv.w, (float)kv[3] + (float)rv[3], s3);
        }
        float p = __expf((s0 + s1) + (s2 + s3) + drk[h * RLEN + jj]);
        p_s[t] = p;
        float ls = p;
#pragma unroll
        for (int off = 32; off > 0; off >>= 1)
            ls += __shfl_down(ls, off, 64);
        if ((t & 63) == 0) lred[t >> 6] = ls;
    }
    __syncthreads();
    {
        const int d = t & 63, g = t >> 6;
        float a0 = 0, a1 = 0;
        const unsigned short* vbase = (const unsigned short*)qkvh
            + (size_t)(b * NSEQ + c0 + g * 32) * HD3 + 1024 + h * 64 + d;
#pragma unroll
        for (int j2 = 0; j2 < 32; j2 += 2) {
            a0 = fmaf(p_s[g * 32 + j2],     bf2f(vbase[(size_t)j2 * HD3]),       a0);
            a1 = fmaf(p_s[g * 32 + j2 + 1], bf2f(vbase[(size_t)(j2 + 1) * HD3]), a1);
        }
        obuf[g][d] = a0 + a1;
    }
    __syncthreads();
    if (t < 64) {
        float o = (obuf[0][t] + obuf[1][t]) + (obuf[2][t] + obuf[3][t]);
        g_O[((size_t)chunk * 64 + bhi) * 64 + t] = o;
        if (t == 0) g_l[chunk * 64 + bhi] = lred[0] + lred[1];
    }
}

// ---------------------------------------------------------------------------
// Overwrite the 64 global rows (i<4 per b,h) of aoh from grows_part partials.
// grid 16 (=bh), 256 thr: i = t>>6, d = t&63.
// ---------------------------------------------------------------------------
__global__ __launch_bounds__(256) void gfix(
    const float* __restrict__ g_O, const float* __restrict__ g_l,
    _Float16* __restrict__ aoh)
{
    const int bh = blockIdx.x, b = bh >> 3, h = bh & 7;
    const int i = threadIdx.x >> 6, d = threadIdx.x & 63;
    const int bhi = bh * 4 + i;
    float o = 0.f, l = 0.f;
#pragma unroll
    for (int c = 0; c < 12; ++c) {
        o += g_O[((size_t)c * 64 + bhi) * 64 + d];
        l += g_l[c * 64 + bhi];
    }
    aoh[((size_t)(b * NSEQ + i)) * 512 + h * 64 + d] = (_Float16)(o / l);
}

// ---------------------------------------------------------------------------
extern "C" void kernel_launch(void* const* d_in, const int* in_sizes, int n_in,
                              void* d_out, int out_size, void* d_ws, size_t ws_size,
                              hipStream_t stream)
{
    const float* x    = (const float*)d_in[0];
    const float* Wq   = (const float*)d_in[1];
    const float* Wk   = (const float*)d_in[2];
    const float* Wv   = (const float*)d_in[3];
    const float* Wrel = (const float*)d_in[4];
    const float* cb   = (const float*)d_in[5];
    const float* rb   = (const float*)d_in[6];
    const float* Wo   = (const float*)d_in[7];
    const float* bo   = (const float*)d_in[8];
    const float* pe   = (const float*)d_in[9];
    float* out = (float*)d_out;

    float* ws = (float*)d_ws;
    _Float16* qkvh = (_Float16*)ws;                      // [3072][1536] Q,K f16 | V bf16
    _Float16* rkh  = (_Float16*)(ws + 2359296);          // [3072][512] f16 (row 3071 scratch)
    float* drk   = ws + 3145728;                         // [8][3071] f32
    _Float16* aoh = (_Float16*)(ws + 3170304);           // [3072][512] f16
    _Float16* woh = (_Float16*)(ws + 3956736);           // WoT [1536][512] f16
    float* R = ws + 4349952;                             // aliased region
    _Float16* relbT = (_Float16*)R;                          // [16][12][512][128] f16
    _Float16* xh  = (_Float16*)R;                            // dead before relbT written
    _Float16* wqh = (_Float16*)(R + 2359296);                // WqkvT [1536][1536] f16
    float* g_O = R + 6291456;                            // [12][64][64] f32 (after relbT)
    float* g_l = R + 6340608;                            // [12][64] f32
    _Float16* peh   = (_Float16*)(ws + 15483648);        // [3072][192] f16 (row 3071 scratch)
    _Float16* wrelT = (_Float16*)(ws + 15778560);        // WrelT [512][192] f16

    dim3 blk(256);
    prep_all<<<6144, blk, 0, stream>>>(x, xh, pe, peh, Wq, Wk, Wv, Wo, Wrel,
                                       wqh, woh, wrelT);
    gemm_f16k<<<dim3(24, 48), blk, 0, stream>>>(xh, wqh, nullptr, qkvh,
                                                3072, 1536, 1536, 1);
    gemm_f16k<<<dim3(8, 48), blk, 0, stream>>>(peh, wrelT, nullptr, rkh,
                                               3072, 512, 192, 2);
    relb_mfma<<<dim3(4, 12, 18), blk, 0, stream>>>(qkvh, rkh, rb, cb, drk, relbT);
    attn_flash<<<dim3(12, 16, 2), blk, 0, stream>>>(qkvh, relbT, rkh, drk, cb, aoh);
    grows_part<<<dim3(12, 64), blk, 0, stream>>>(qkvh, rkh, drk, cb, g_O, g_l);
    gfix<<<16, blk, 0, stream>>>(g_O, g_l, aoh);
    gemm_f16k<<<dim3(24, 48), blk, 0, stream>>>(aoh, woh, bo, out,
                                                3072, 1536, 512, 0);
}